// Round 6
// baseline (223.095 us; speedup 1.0000x reference)
//
#include <hip/hip_runtime.h>
#include <hip/hip_bf16.h>
#include <stdint.h>

// ---------------------------------------------------------------------------
// SelfAttention2d: B=4, C=256, H=W=64 (N=4096), NUM_HEADS=4 (hd=64), GROUPS=8
// R5: flash v5 — barrier-free K-loop: 4 waves share one 64-q tile with 4-way
//     key split and PER-WAVE private single-buffered K/V LDS streams (own-wave
//     vmcnt(0) is the only sync). Grid 1024, LDS 39936 B -> 3 blocks/CU
//     (12 waves/CU). Exact merge tree at end. qkv: 256-o blocks (staging /4).
//     proj: 128-o blocks (staging /2).
// ---------------------------------------------------------------------------

#define B_  4
#define C_  256
#define N_  4096
#define NH_ 4
#define HD_ 64
#define G_  8
#define CPG_ 32
#define GRP_ELEMS (CPG_ * N_)

typedef __attribute__((ext_vector_type(8))) short short8;
typedef __attribute__((ext_vector_type(4))) float f32x4;
typedef __attribute__((ext_vector_type(4))) unsigned short us4;

__device__ __forceinline__ unsigned short f2bf(float f) {
  union { float f; unsigned u; } v; v.f = f;
  unsigned r = v.u + 0x7FFFu + ((v.u >> 16) & 1u);
  return (unsigned short)(r >> 16);
}

// packed fp32x2 -> bf16x2 (v_cvt_pk_bf16_f32 on gfx950)
__device__ __forceinline__ unsigned pkbf2(float a, float b) {
  __hip_bfloat162 h = __float22bfloat162_rn(make_float2(a, b));
  unsigned r; __builtin_memcpy(&r, &h, sizeof(r)); return r;
}

// async 16B/lane global->LDS DMA; LDS dest = uniform base + lane*16
__device__ __forceinline__ void dma16(const unsigned short* g, unsigned short* l) {
  __builtin_amdgcn_global_load_lds(
      (const __attribute__((address_space(1))) unsigned int*)(g),
      (__attribute__((address_space(3))) unsigned int*)(l), 16, 0, 0);
}

// ---------------------------------------------------------------------------
// Kernel 1: convert qkv_w (768x256) and proj_w (256x256) fp32 -> bf16
// ---------------------------------------------------------------------------
__global__ void cvt_weights(const float* __restrict__ qkvw,
                            const float* __restrict__ projw,
                            unsigned short* __restrict__ wq,
                            unsigned short* __restrict__ wp) {
  int i = blockIdx.x * 256 + threadIdx.x;
  if (i < 768 * 256) wq[i] = f2bf(qkvw[i]);
  if (i < 256 * 256) wp[i] = f2bf(projw[i]);
}

// ---------------------------------------------------------------------------
// Kernel 2: groupnorm partial sums. 512 blocks = (b,g,slice16), 256 threads.
// ---------------------------------------------------------------------------
__global__ void gn_partial(const float* __restrict__ x, float* __restrict__ partial) {
  int idx = blockIdx.x;
  int slice = idx & 15, g = (idx >> 4) & 7, b = idx >> 7;
  int t = threadIdx.x;
  const float* base = x + (size_t)(b * C_ + g * CPG_) * N_ + slice * 256;
  float s = 0.f, sq = 0.f;
#pragma unroll
  for (int cc = 0; cc < CPG_; cc++) {
    float v = base[(size_t)cc * N_ + t];
    s += v; sq += v * v;
  }
#pragma unroll
  for (int off = 32; off; off >>= 1) {
    s  += __shfl_down(s,  off, 64);
    sq += __shfl_down(sq, off, 64);
  }
  __shared__ float ls[8];
  int wave = t >> 6, lane = t & 63;
  if (lane == 0) { ls[wave * 2] = s; ls[wave * 2 + 1] = sq; }
  __syncthreads();
  if (t == 0) {
    float S = ls[0] + ls[2] + ls[4] + ls[6];
    float SQ = ls[1] + ls[3] + ls[5] + ls[7];
    partial[idx * 2] = S; partial[idx * 2 + 1] = SQ;
  }
}

// ---------------------------------------------------------------------------
// Kernel 3: finalize stats. 32 groups, stats[g] = {mean, rstd}
// ---------------------------------------------------------------------------
__global__ void gn_finalize(const float* __restrict__ partial, float* __restrict__ stats) {
  int t = threadIdx.x;
  if (t < 32) {
    float s = 0.f, sq = 0.f;
    for (int i = 0; i < 16; i++) {
      s  += partial[(t * 16 + i) * 2];
      sq += partial[(t * 16 + i) * 2 + 1];
    }
    const float inv = 1.0f / (float)GRP_ELEMS;
    float mean = s * inv;
    float var = sq * inv - mean * mean;
    stats[t * 2] = mean;
    stats[t * 2 + 1] = rsqrtf(var + 1e-5f);
  }
}

// ---------------------------------------------------------------------------
// Kernel 4: normalize + transpose. x (B,C,N) fp32 -> hT (B,N,C) bf16.
// ---------------------------------------------------------------------------
__global__ void gn_apply(const float* __restrict__ x,
                         const float* __restrict__ nw, const float* __restrict__ nb,
                         const float* __restrict__ stats, unsigned short* __restrict__ hT) {
  int nt = blockIdx.x, ct = blockIdx.y, b = blockIdx.z;
  __shared__ unsigned short tile[32][72];
  int t = threadIdx.x;
  int n_loc = t & 63, c_loc = t >> 6;
  float mean = stats[(b * G_ + ct) * 2];
  float rstd = stats[(b * G_ + ct) * 2 + 1];
  const float* xb = x + (size_t)(b * C_ + ct * CPG_) * N_ + nt * 64;
#pragma unroll
  for (int rr = 0; rr < 8; rr++) {
    int cc = rr * 4 + c_loc;
    int c = ct * CPG_ + cc;
    float v = xb[(size_t)cc * N_ + n_loc];
    v = (v - mean) * rstd * nw[c] + nb[c];
    tile[cc][n_loc] = f2bf(v);
  }
  __syncthreads();
  int c2 = t & 31, n2 = t >> 5;
  unsigned short* out = hT + ((size_t)(b * N_ + nt * 64)) * C_ + ct * CPG_ + c2;
#pragma unroll
  for (int pass = 0; pass < 8; pass++) {
    int n = pass * 8 + n2;
    out[(size_t)n * C_] = tile[c2][n];
  }
}

// ---------------------------------------------------------------------------
// Kernel 5: qkv GEMM. grid (64 nt, 3 sec, 4 b). Block covers 256 outputs
// (wave = 64 consecutive o = exactly one head), so the shared hT tile is
// staged once per (nt,sec,b) -> 4x less staging redundancy than R4.
// ---------------------------------------------------------------------------
__global__ __launch_bounds__(256) void qkv_gemm(
    const unsigned short* __restrict__ hT, const unsigned short* __restrict__ wq,
    const float* __restrict__ qb,
    unsigned short* __restrict__ Qt, unsigned short* __restrict__ Kt,
    unsigned short* __restrict__ V) {
  int nt = blockIdx.x, sec = blockIdx.y, b = blockIdx.z;
  int t = threadIdx.x;
  int wave = t >> 6, lane = t & 63, l15 = lane & 15, quad = lane >> 4, l7 = l15 & 7;

  __shared__ __align__(16) unsigned short sh[64 * C_];
  {
    int row0 = wave * 2 + (lane >> 5);
    int col8 = lane & 31;
    int src8 = (col8 & 24) | ((col8 & 7) ^ (row0 & 7));
    const unsigned short* gsrc = hT + ((size_t)(b * N_ + nt * 64 + row0)) * C_ + src8 * 8;
#pragma unroll
    for (int it = 0; it < 8; it++)
      dma16(gsrc + (size_t)it * 8 * C_, sh + (it * 8 + wave * 2) * C_);
  }

  f32x4 acc[4][4];
#pragma unroll
  for (int r = 0; r < 4; r++)
#pragma unroll
    for (int tt = 0; tt < 4; tt++) acc[r][tt] = (f32x4){0.f, 0.f, 0.f, 0.f};

  const short8* arow[4];
#pragma unroll
  for (int r = 0; r < 4; r++)
    arow[r] = reinterpret_cast<const short8*>(
        wq + (size_t)(sec * 256 + wave * 64 + r * 16 + l15) * C_);

  asm volatile("s_waitcnt vmcnt(0)" ::: "memory");
  __syncthreads();

#pragma unroll
  for (int kk = 0; kk < 8; kk++) {
    int g = kk * 4 + quad;
    int col8 = (g & 24) | ((g & 7) ^ l7);
    short8 bfr[4];
#pragma unroll
    for (int tt = 0; tt < 4; tt++)
      bfr[tt] = *reinterpret_cast<const short8*>(&sh[(tt * 16 + l15) * C_ + col8 * 8]);
#pragma unroll
    for (int r = 0; r < 4; r++) {
      short8 a = arow[r][g];
#pragma unroll
      for (int tt = 0; tt < 4; tt++)
        acc[r][tt] = __builtin_amdgcn_mfma_f32_16x16x32_bf16(a, bfr[tt], acc[r][tt], 0, 0, 0);
    }
  }

  int head = wave;
  int bh = b * NH_ + head;
  const float SC = 0.125f * 1.44269504088896340736f;  // 1/sqrt(hd) * log2(e)

  if (sec == 0) {
#pragma unroll
    for (int r = 0; r < 4; r++) {
      int cw = r * 16 + quad * 4;
#pragma unroll
      for (int tt = 0; tt < 4; tt++) {
        int n = nt * 64 + tt * 16 + l15;
        us4 pk;
#pragma unroll
        for (int i = 0; i < 4; i++)
          pk[i] = f2bf((acc[r][tt][i] + qb[wave * 64 + cw + i]) * SC);
        *reinterpret_cast<us4*>(Qt + ((size_t)bh * N_ + n) * HD_ + cw) = pk;
      }
    }
  } else if (sec == 1) {
#pragma unroll
    for (int r = 0; r < 4; r++) {
      int cw = r * 16 + quad * 4;
#pragma unroll
      for (int tt = 0; tt < 4; tt++) {
        int n = nt * 64 + tt * 16 + l15;
        us4 pk;
#pragma unroll
        for (int i = 0; i < 4; i++)
          pk[i] = f2bf(acc[r][tt][i] + qb[256 + wave * 64 + cw + i]);
        *reinterpret_cast<us4*>(Kt + ((size_t)bh * N_ + n) * HD_ + cw) = pk;
      }
    }
  } else {
#pragma unroll
    for (int r = 0; r < 4; r++) {
      int cw = r * 16 + quad * 4;
#pragma unroll
      for (int tt = 0; tt < 4; tt++) {
        int n = nt * 64 + tt * 16 + l15;
#pragma unroll
        for (int i = 0; i < 4; i++)
          V[((size_t)bh * HD_ + cw + i) * N_ + n] =
              f2bf(acc[r][tt][i] + qb[512 + wave * 64 + cw + i]);
      }
    }
  }
}

// ---------------------------------------------------------------------------
// Kernel 6: flash attention v5 — barrier-free K-loop.
// Grid 1024 = (bh = blockIdx&15, qt = blockIdx>>4). Block: 4 waves, same
// 64-q tile, wave w handles keys [w*1024, (w+1)*1024) in 32-key tiles.
// Each wave has a PRIVATE single-buffered K/V LDS stream staged via
// global_load_lds; own-wave vmcnt(0) is the only staging sync. Exact
// merge (plain O/l adds) via LDS tree at the end.
// ---------------------------------------------------------------------------
__global__ __launch_bounds__(256, 3) void flash_attn(
    const unsigned short* __restrict__ Qt, const unsigned short* __restrict__ Kt,
    const unsigned short* __restrict__ Vv, unsigned short* __restrict__ aoT) {
  int bh = blockIdx.x & 15, qt = blockIdx.x >> 4;
  int b = bh >> 2, head = bh & 3;
  int t = threadIdx.x;
  int wave = t >> 6, lane = t & 63, l15 = lane & 15, quad = lane >> 4;
  int l7 = l15 & 7;

  const unsigned short* Qb = Qt + (size_t)bh * N_ * HD_;
  const unsigned short* Kb = Kt + (size_t)bh * N_ * HD_;
  const unsigned short* Vb = Vv + (size_t)bh * HD_ * N_;
  int q_base = qt * 64;

  // LDS: K[4 waves][32key x 64ch]=16K, V[4][64c x 32key]=16K, P[4][16q x 56]=7K
  __shared__ __align__(16) unsigned char smem[39936];
  unsigned short* Kw = (unsigned short*)(smem + wave * 4096);
  unsigned short* Vw = (unsigned short*)(smem + 16384 + wave * 4096);
  unsigned short* Pw = (unsigned short*)(smem + 32768 + wave * 1792);
  float* ObA = (float*)smem;                  // 64c x 68 stride, 17408 B
  float* ObB = (float*)(smem + 17408);
  float* lbA = (float*)(smem + 34816);
  float* lbB = (float*)(smem + 35072);

  const short8 vones = {(short)0x3F80, (short)0x3F80, (short)0x3F80, (short)0x3F80,
                        (short)0x3F80, (short)0x3F80, (short)0x3F80, (short)0x3F80};

  // Q B-fragments (same 64 q for all waves)
  short8 qf[4][2];
#pragma unroll
  for (int r = 0; r < 4; r++)
#pragma unroll
    for (int h = 0; h < 2; h++)
      qf[r][h] = *reinterpret_cast<const short8*>(
          Qb + (size_t)(q_base + r * 16 + l15) * HD_ + h * 32 + quad * 8);

  f32x4 oa[4][4], la[4];
#pragma unroll
  for (int r = 0; r < 4; r++) {
    la[r] = (f32x4){0.f, 0.f, 0.f, 0.f};
#pragma unroll
    for (int ct = 0; ct < 4; ct++) oa[r][ct] = (f32x4){0.f, 0.f, 0.f, 0.f};
  }

  int key0 = wave * 1024;
  int i8 = lane >> 3, e8 = lane & 7;     // K staging geometry
  int r16 = lane >> 2, e4 = lane & 3;    // V staging geometry
  int kperm = (e8 ^ i8) * 8;
  int vperm = (e4 ^ ((r16 >> 1) & 3)) * 8;

  auto stage = [&](int kt2) {
    int m0 = key0 + kt2 * 32;
#pragma unroll
    for (int cc = 0; cc < 4; cc++)   // K: 4 chunks of 8 key-rows (64 ch each)
      dma16(Kb + (size_t)(m0 + cc * 8 + i8) * HD_ + kperm, Kw + cc * 512);
#pragma unroll
    for (int cc = 0; cc < 4; cc++)   // V: 4 chunks of 16 c-rows (32 keys each)
      dma16(Vb + (size_t)(cc * 16 + r16) * N_ + m0 + vperm, Vw + cc * 512);
  };

  stage(0);

#pragma unroll 1
  for (int kt = 0; kt < 32; kt++) {
    asm volatile("s_waitcnt vmcnt(0)" ::: "memory");   // own DMA landed

    // K A-frags: key = tt*16+l15 (tt 0..1), ch granule swizzled by l7
    short8 kf[2][2];
#pragma unroll
    for (int tt = 0; tt < 2; tt++)
#pragma unroll
      for (int kh = 0; kh < 2; kh++)
        kf[tt][kh] = *reinterpret_cast<const short8*>(
            &Kw[(tt * 16 + l15) * 64 + (((kh * 4 + quad) ^ l7) * 8)]);
    // V A-frags: c = ct*16+l15, key granule = quad swizzled by (l15>>1)&3
    short8 vf[4];
#pragma unroll
    for (int ct = 0; ct < 4; ct++)
      vf[ct] = *reinterpret_cast<const short8*>(
          &Vw[(ct * 16 + l15) * 32 + ((quad ^ ((l15 >> 1) & 3)) * 8)]);

    asm volatile("s_waitcnt lgkmcnt(0)" ::: "memory"); // frags in regs
    if (kt + 1 < 32) stage(kt + 1);                    // restage overlaps compute

#pragma unroll
    for (int r = 0; r < 4; r++) {
      f32x4 s0, s1;
      {
        f32x4 z = (f32x4){0.f, 0.f, 0.f, 0.f};
        z  = __builtin_amdgcn_mfma_f32_16x16x32_bf16(kf[0][0], qf[r][0], z, 0, 0, 0);
        s0 = __builtin_amdgcn_mfma_f32_16x16x32_bf16(kf[0][1], qf[r][1], z, 0, 0, 0);
      }
      {
        f32x4 z = (f32x4){0.f, 0.f, 0.f, 0.f};
        z  = __builtin_amdgcn_mfma_f32_16x16x32_bf16(kf[1][0], qf[r][0], z, 0, 0, 0);
        s1 = __builtin_amdgcn_mfma_f32_16x16x32_bf16(kf[1][1], qf[r][1], z, 0, 0, 0);
      }
      union { unsigned u2[2]; us4 v; } w0, w1;
      w0.u2[0] = pkbf2(__builtin_amdgcn_exp2f(s0[0]), __builtin_amdgcn_exp2f(s0[1]));
      w0.u2[1] = pkbf2(__builtin_amdgcn_exp2f(s0[2]), __builtin_amdgcn_exp2f(s0[3]));
      w1.u2[0] = pkbf2(__builtin_amdgcn_exp2f(s1[0]), __builtin_amdgcn_exp2f(s1[1]));
      w1.u2[1] = pkbf2(__builtin_amdgcn_exp2f(s1[2]), __builtin_amdgcn_exp2f(s1[3]));
      *reinterpret_cast<us4*>(&Pw[l15 * 56 + quad * 4]) = w0.v;       // keys 0..15
      *reinterpret_cast<us4*>(&Pw[l15 * 56 + 16 + quad * 4]) = w1.v;  // keys 16..31
      short8 pf = *reinterpret_cast<const short8*>(&Pw[l15 * 56 + quad * 8]);
#pragma unroll
      for (int ct = 0; ct < 4; ct++)
        oa[r][ct] = __builtin_amdgcn_mfma_f32_16x16x32_bf16(vf[ct], pf, oa[r][ct], 0, 0, 0);
      la[r] = __builtin_amdgcn_mfma_f32_16x16x32_bf16(vones, pf, la[r], 0, 0, 0);
    }
  }

  // ---- exact merge tree over the 4 key-quarter partials ----
  __syncthreads();
  if (wave == 1 || wave == 3) {
    float* Ob = (wave == 1) ? ObA : ObB;
    float* lb = (wave == 1) ? lbA : lbB;
#pragma unroll
    for (int r = 0; r < 4; r++) {
#pragma unroll
      for (int ct = 0; ct < 4; ct++)
#pragma unroll
        for (int i = 0; i < 4; i++)
          Ob[(ct * 16 + quad * 4 + i) * 68 + r * 16 + l15] = oa[r][ct][i];
      if (quad == 0) lb[r * 16 + l15] = la[r][0];
    }
  }
  __syncthreads();
  if (wave == 0 || wave == 2) {
    const float* Ob = (wave == 0) ? ObA : ObB;
    const float* lb = (wave == 0) ? lbA : lbB;
#pragma unroll
    for (int r = 0; r < 4; r++) {
      la[r][0] += lb[r * 16 + l15];
#pragma unroll
      for (int ct = 0; ct < 4; ct++)
#pragma unroll
        for (int i = 0; i < 4; i++)
          oa[r][ct][i] += Ob[(ct * 16 + quad * 4 + i) * 68 + r * 16 + l15];
    }
  }
  __syncthreads();
  if (wave == 2) {
#pragma unroll
    for (int r = 0; r < 4; r++) {
#pragma unroll
      for (int ct = 0; ct < 4; ct++)
#pragma unroll
        for (int i = 0; i < 4; i++)
          ObA[(ct * 16 + quad * 4 + i) * 68 + r * 16 + l15] = oa[r][ct][i];
      if (quad == 0) lbA[r * 16 + l15] = la[r][0];
    }
  }
  __syncthreads();
  if (wave == 0) {
#pragma unroll
    for (int r = 0; r < 4; r++) {
      float inv = 1.0f / (la[r][0] + lbA[r * 16 + l15]);
      int n = q_base + r * 16 + l15;
#pragma unroll
      for (int ct = 0; ct < 4; ct++) {
        const float* ob = &ObA[(ct * 16 + quad * 4) * 68 + r * 16 + l15];
        union { unsigned u2[2]; us4 v; } w;
        w.u2[0] = pkbf2((oa[r][ct][0] + ob[0]) * inv, (oa[r][ct][1] + ob[68]) * inv);
        w.u2[1] = pkbf2((oa[r][ct][2] + ob[136]) * inv, (oa[r][ct][3] + ob[204]) * inv);
        *reinterpret_cast<us4*>(
            aoT + ((size_t)(b * N_ + n)) * C_ + head * HD_ + ct * 16 + quad * 4) = w.v;
      }
    }
  }
}

// ---------------------------------------------------------------------------
// Kernel 7: proj GEMM + bias + residual. grid (64 nt, 2 ot, 4 b); block
// covers 128 outputs (wave = 32 o) -> staging redundancy 2 (was 4).
// ---------------------------------------------------------------------------
__global__ __launch_bounds__(256) void proj_gemm(
    const unsigned short* __restrict__ aoT, const unsigned short* __restrict__ wp,
    const float* __restrict__ pb, const float* __restrict__ x,
    float* __restrict__ out) {
  int nt = blockIdx.x, ot = blockIdx.y, b = blockIdx.z;
  int t = threadIdx.x;
  int wave = t >> 6, lane = t & 63, l15 = lane & 15, quad = lane >> 4, l7 = l15 & 7;
  int o_base = ot * 128 + wave * 32;

  __shared__ __align__(16) unsigned short sh[64 * C_];
  {
    int row0 = wave * 2 + (lane >> 5);
    int col8 = lane & 31;
    int src8 = (col8 & 24) | ((col8 & 7) ^ (row0 & 7));
    const unsigned short* gsrc = aoT + ((size_t)(b * N_ + nt * 64 + row0)) * C_ + src8 * 8;
#pragma unroll
    for (int it = 0; it < 8; it++)
      dma16(gsrc + (size_t)it * 8 * C_, sh + (it * 8 + wave * 2) * C_);
  }

  f32x4 acc[2][4];
#pragma unroll
  for (int r = 0; r < 2; r++)
#pragma unroll
    for (int tt = 0; tt < 4; tt++) acc[r][tt] = (f32x4){0.f, 0.f, 0.f, 0.f};

  const short8* arow[2];
#pragma unroll
  for (int r = 0; r < 2; r++)
    arow[r] = reinterpret_cast<const short8*>(wp + (size_t)(o_base + r * 16 + l15) * C_);

  asm volatile("s_waitcnt vmcnt(0)" ::: "memory");
  __syncthreads();

#pragma unroll
  for (int kk = 0; kk < 8; kk++) {
    int g = kk * 4 + quad;
    int col8 = (g & 24) | ((g & 7) ^ l7);
    short8 bfr[4];
#pragma unroll
    for (int tt = 0; tt < 4; tt++)
      bfr[tt] = *reinterpret_cast<const short8*>(&sh[(tt * 16 + l15) * C_ + col8 * 8]);
#pragma unroll
    for (int r = 0; r < 2; r++) {
      short8 a = arow[r][g];
#pragma unroll
      for (int tt = 0; tt < 4; tt++)
        acc[r][tt] = __builtin_amdgcn_mfma_f32_16x16x32_bf16(a, bfr[tt], acc[r][tt], 0, 0, 0);
    }
  }
#pragma unroll
  for (int r = 0; r < 2; r++)
#pragma unroll
    for (int tt = 0; tt < 4; tt++) {
      int n = nt * 64 + tt * 16 + l15;
#pragma unroll
      for (int i = 0; i < 4; i++) {
        int o = o_base + r * 16 + quad * 4 + i;
        size_t idx = ((size_t)(b * C_ + o)) * N_ + n;
        out[idx] = acc[r][tt][i] + pb[o] + x[idx];
      }
    }
}

// ---------------------------------------------------------------------------
extern "C" void kernel_launch(void* const* d_in, const int* in_sizes, int n_in,
                              void* d_out, int out_size, void* d_ws, size_t ws_size,
                              hipStream_t stream) {
  const float* x      = (const float*)d_in[0];
  const float* norm_w = (const float*)d_in[1];
  const float* norm_b = (const float*)d_in[2];
  const float* qkv_w  = (const float*)d_in[3];
  const float* qkv_b  = (const float*)d_in[4];
  const float* proj_w = (const float*)d_in[5];
  const float* proj_b = (const float*)d_in[6];
  float* out = (float*)d_out;

  char* ws = (char*)d_ws;
  size_t off = 0;
  auto alloc = [&](size_t bytes) { size_t o = off; off = (off + bytes + 255) & ~(size_t)255; return o; };
  size_t off_partial = alloc(512 * 2 * sizeof(float));
  size_t off_stats   = alloc(32 * 2 * sizeof(float));
  size_t off_wq      = alloc((size_t)768 * 256 * 2);
  size_t off_wp      = alloc((size_t)256 * 256 * 2);
  size_t off_hT      = alloc((size_t)B_ * N_ * C_ * 2);
  size_t off_Qt      = alloc((size_t)B_ * NH_ * N_ * HD_ * 2);
  size_t off_Kt      = alloc((size_t)B_ * NH_ * N_ * HD_ * 2);
  size_t off_V       = alloc((size_t)B_ * NH_ * HD_ * N_ * 2);
  size_t off_aoT     = alloc((size_t)B_ * N_ * C_ * 2);

  float* partial = (float*)(ws + off_partial);
  float* stats   = (float*)(ws + off_stats);
  unsigned short* wq  = (unsigned short*)(ws + off_wq);
  unsigned short* wp  = (unsigned short*)(ws + off_wp);
  unsigned short* hT  = (unsigned short*)(ws + off_hT);
  unsigned short* Qt  = (unsigned short*)(ws + off_Qt);
  unsigned short* Kt  = (unsigned short*)(ws + off_Kt);
  unsigned short* V   = (unsigned short*)(ws + off_V);
  unsigned short* aoT = (unsigned short*)(ws + off_aoT);

  cvt_weights<<<768, 256, 0, stream>>>(qkv_w, proj_w, wq, wp);
  gn_partial<<<512, 256, 0, stream>>>(x, partial);
  gn_finalize<<<1, 64, 0, stream>>>(partial, stats);
  gn_apply<<<dim3(64, 8, 4), 256, 0, stream>>>(x, norm_w, norm_b, stats, hT);
  qkv_gemm<<<dim3(64, 3, 4), 256, 0, stream>>>(hT, wq, qkv_b, Qt, Kt, V);
  flash_attn<<<1024, 256, 0, stream>>>(Qt, Kt, V, aoT);
  proj_gemm<<<dim3(64, 2, 4), 256, 0, stream>>>(aoT, wp, proj_b, x, out);
}

// Round 7
// 209.459 us; speedup vs baseline: 1.0651x; 1.0651x over previous
//
#include <hip/hip_runtime.h>
#include <hip/hip_bf16.h>
#include <stdint.h>

// ---------------------------------------------------------------------------
// SelfAttention2d: B=4, C=256, H=W=64 (N=4096), NUM_HEADS=4 (hd=64), GROUPS=8
// R6: flash v6 — R4 geometry (wave=64q, 2 qsub x 2 khalf, grid 512) with
//     PRIVATE per-wave double-buffered K/V streams and ZERO barriers in the
//     K-loop (own-wave vmcnt(0) is the only sync; DMA has a full iteration
//     to land). 32-key tiles. qkv/proj reverted to R4 versions.
// ---------------------------------------------------------------------------

#define B_  4
#define C_  256
#define N_  4096
#define NH_ 4
#define HD_ 64
#define G_  8
#define CPG_ 32
#define GRP_ELEMS (CPG_ * N_)

typedef __attribute__((ext_vector_type(8))) short short8;
typedef __attribute__((ext_vector_type(4))) float f32x4;
typedef __attribute__((ext_vector_type(4))) unsigned short us4;

__device__ __forceinline__ unsigned short f2bf(float f) {
  union { float f; unsigned u; } v; v.f = f;
  unsigned r = v.u + 0x7FFFu + ((v.u >> 16) & 1u);
  return (unsigned short)(r >> 16);
}

// packed fp32x2 -> bf16x2 (v_cvt_pk_bf16_f32 on gfx950)
__device__ __forceinline__ unsigned pkbf2(float a, float b) {
  __hip_bfloat162 h = __float22bfloat162_rn(make_float2(a, b));
  unsigned r; __builtin_memcpy(&r, &h, sizeof(r)); return r;
}

// async 16B/lane global->LDS DMA; LDS dest = uniform base + lane*16
__device__ __forceinline__ void dma16(const unsigned short* g, unsigned short* l) {
  __builtin_amdgcn_global_load_lds(
      (const __attribute__((address_space(1))) unsigned int*)(g),
      (__attribute__((address_space(3))) unsigned int*)(l), 16, 0, 0);
}

// ---------------------------------------------------------------------------
// Kernel 1: convert qkv_w (768x256) and proj_w (256x256) fp32 -> bf16
// ---------------------------------------------------------------------------
__global__ void cvt_weights(const float* __restrict__ qkvw,
                            const float* __restrict__ projw,
                            unsigned short* __restrict__ wq,
                            unsigned short* __restrict__ wp) {
  int i = blockIdx.x * 256 + threadIdx.x;
  if (i < 768 * 256) wq[i] = f2bf(qkvw[i]);
  if (i < 256 * 256) wp[i] = f2bf(projw[i]);
}

// ---------------------------------------------------------------------------
// Kernel 2: groupnorm partial sums. 512 blocks = (b,g,slice16), 256 threads.
// ---------------------------------------------------------------------------
__global__ void gn_partial(const float* __restrict__ x, float* __restrict__ partial) {
  int idx = blockIdx.x;
  int slice = idx & 15, g = (idx >> 4) & 7, b = idx >> 7;
  int t = threadIdx.x;
  const float* base = x + (size_t)(b * C_ + g * CPG_) * N_ + slice * 256;
  float s = 0.f, sq = 0.f;
#pragma unroll
  for (int cc = 0; cc < CPG_; cc++) {
    float v = base[(size_t)cc * N_ + t];
    s += v; sq += v * v;
  }
#pragma unroll
  for (int off = 32; off; off >>= 1) {
    s  += __shfl_down(s,  off, 64);
    sq += __shfl_down(sq, off, 64);
  }
  __shared__ float ls[8];
  int wave = t >> 6, lane = t & 63;
  if (lane == 0) { ls[wave * 2] = s; ls[wave * 2 + 1] = sq; }
  __syncthreads();
  if (t == 0) {
    float S = ls[0] + ls[2] + ls[4] + ls[6];
    float SQ = ls[1] + ls[3] + ls[5] + ls[7];
    partial[idx * 2] = S; partial[idx * 2 + 1] = SQ;
  }
}

// ---------------------------------------------------------------------------
// Kernel 3: finalize stats. 32 groups, stats[g] = {mean, rstd}
// ---------------------------------------------------------------------------
__global__ void gn_finalize(const float* __restrict__ partial, float* __restrict__ stats) {
  int t = threadIdx.x;
  if (t < 32) {
    float s = 0.f, sq = 0.f;
    for (int i = 0; i < 16; i++) {
      s  += partial[(t * 16 + i) * 2];
      sq += partial[(t * 16 + i) * 2 + 1];
    }
    const float inv = 1.0f / (float)GRP_ELEMS;
    float mean = s * inv;
    float var = sq * inv - mean * mean;
    stats[t * 2] = mean;
    stats[t * 2 + 1] = rsqrtf(var + 1e-5f);
  }
}

// ---------------------------------------------------------------------------
// Kernel 4: normalize + transpose. x (B,C,N) fp32 -> hT (B,N,C) bf16.
// ---------------------------------------------------------------------------
__global__ void gn_apply(const float* __restrict__ x,
                         const float* __restrict__ nw, const float* __restrict__ nb,
                         const float* __restrict__ stats, unsigned short* __restrict__ hT) {
  int nt = blockIdx.x, ct = blockIdx.y, b = blockIdx.z;
  __shared__ unsigned short tile[32][72];
  int t = threadIdx.x;
  int n_loc = t & 63, c_loc = t >> 6;
  float mean = stats[(b * G_ + ct) * 2];
  float rstd = stats[(b * G_ + ct) * 2 + 1];
  const float* xb = x + (size_t)(b * C_ + ct * CPG_) * N_ + nt * 64;
#pragma unroll
  for (int rr = 0; rr < 8; rr++) {
    int cc = rr * 4 + c_loc;
    int c = ct * CPG_ + cc;
    float v = xb[(size_t)cc * N_ + n_loc];
    v = (v - mean) * rstd * nw[c] + nb[c];
    tile[cc][n_loc] = f2bf(v);
  }
  __syncthreads();
  int c2 = t & 31, n2 = t >> 5;
  unsigned short* out = hT + ((size_t)(b * N_ + nt * 64)) * C_ + ct * CPG_ + c2;
#pragma unroll
  for (int pass = 0; pass < 8; pass++) {
    int n = pass * 8 + n2;
    out[(size_t)n * C_] = tile[c2][n];
  }
}

// ---------------------------------------------------------------------------
// Kernel 5: qkv GEMM (R4 version). D[o][n] = sum_c Wqkv[o][c]*hT[n][c]+bias.
// hT tile (64n x 256c) staged in LDS once per block (xor-swizzled).
// ---------------------------------------------------------------------------
__global__ __launch_bounds__(256) void qkv_gemm(
    const unsigned short* __restrict__ hT, const unsigned short* __restrict__ wq,
    const float* __restrict__ qb,
    unsigned short* __restrict__ Qt, unsigned short* __restrict__ Kt,
    unsigned short* __restrict__ V) {
  int nt = blockIdx.x, ot = blockIdx.y, b = blockIdx.z;
  int t = threadIdx.x;
  int wave = t >> 6, lane = t & 63, l15 = lane & 15, quad = lane >> 4, l7 = l15 & 7;
  int o_base = ot * 64 + wave * 16;

  __shared__ __align__(16) unsigned short sh[64 * C_];
  {
    int row0 = wave * 2 + (lane >> 5);
    int col8 = lane & 31;
    int src8 = (col8 & 24) | ((col8 & 7) ^ (row0 & 7));
    const unsigned short* gsrc = hT + ((size_t)(b * N_ + nt * 64 + row0)) * C_ + src8 * 8;
#pragma unroll
    for (int it = 0; it < 8; it++)
      dma16(gsrc + (size_t)it * 8 * C_, sh + (it * 8 + wave * 2) * C_);
  }

  f32x4 acc[4];
#pragma unroll
  for (int tt = 0; tt < 4; tt++) acc[tt] = (f32x4){0.f, 0.f, 0.f, 0.f};

  const short8* arow = reinterpret_cast<const short8*>(wq + (size_t)(o_base + l15) * C_);

  asm volatile("s_waitcnt vmcnt(0)" ::: "memory");
  __syncthreads();

#pragma unroll
  for (int kk = 0; kk < 8; kk++) {
    short8 a = arow[kk * 4 + quad];
    int g = kk * 4 + quad;
    int col8 = (g & 24) | ((g & 7) ^ l7);
#pragma unroll
    for (int tt = 0; tt < 4; tt++) {
      short8 bf = *reinterpret_cast<const short8*>(&sh[(tt * 16 + l15) * C_ + col8 * 8]);
      acc[tt] = __builtin_amdgcn_mfma_f32_16x16x32_bf16(a, bf, acc[tt], 0, 0, 0);
    }
  }

  int sec = ot >> 2, head = ot & 3;
  int cw = wave * 16 + quad * 4;
  int bh = b * NH_ + head;
  const float SC = 0.125f * 1.44269504088896340736f;  // 1/sqrt(hd) * log2(e)

  if (sec == 0) {
#pragma unroll
    for (int tt = 0; tt < 4; tt++) {
      int n = nt * 64 + tt * 16 + l15;
      us4 pk;
#pragma unroll
      for (int i = 0; i < 4; i++)
        pk[i] = f2bf((acc[tt][i] + qb[ot * 64 + cw + i]) * SC);
      *reinterpret_cast<us4*>(Qt + ((size_t)bh * N_ + n) * HD_ + cw) = pk;
    }
  } else if (sec == 1) {
#pragma unroll
    for (int tt = 0; tt < 4; tt++) {
      int n = nt * 64 + tt * 16 + l15;
      us4 pk;
#pragma unroll
      for (int i = 0; i < 4; i++)
        pk[i] = f2bf(acc[tt][i] + qb[ot * 64 + cw + i]);
      *reinterpret_cast<us4*>(Kt + ((size_t)bh * N_ + n) * HD_ + cw) = pk;
    }
  } else {
#pragma unroll
    for (int tt = 0; tt < 4; tt++) {
      int n = nt * 64 + tt * 16 + l15;
#pragma unroll
      for (int i = 0; i < 4; i++)
        V[((size_t)bh * HD_ + cw + i) * N_ + n] = f2bf(acc[tt][i] + qb[ot * 64 + cw + i]);
    }
  }
}

// ---------------------------------------------------------------------------
// Kernel 6: flash attention v6 — barrier-free K-loop, private double-buffered
// per-wave K/V streams. Grid 512 = (bh = blockIdx&15, qt = blockIdx>>4).
// Block: 4 waves = qsub(wave>>1) x khalf(wave&1). Wave: 64 q x 2048 keys in
// 64 tiles of 32 keys. Per iter: vmcnt(0) waits only own stage (issued one
// full iteration earlier), restage buf^1, compute. No s_barrier until merge.
// ---------------------------------------------------------------------------
__global__ __launch_bounds__(256, 2) void flash_attn(
    const unsigned short* __restrict__ Qt, const unsigned short* __restrict__ Kt,
    const unsigned short* __restrict__ Vv, unsigned short* __restrict__ aoT) {
  int bh = blockIdx.x & 15, qt = blockIdx.x >> 4;
  int b = bh >> 2, head = bh & 3;
  int t = threadIdx.x;
  int wave = t >> 6, lane = t & 63, l15 = lane & 15, quad = lane >> 4;
  int l7 = l15 & 7;
  int qsub = wave >> 1, khalf = wave & 1;

  const unsigned short* Qb = Qt + (size_t)bh * N_ * HD_;
  const unsigned short* Kb = Kt + (size_t)bh * N_ * HD_;
  const unsigned short* Vb = Vv + (size_t)bh * HD_ * N_;
  int q_base = qt * 128 + qsub * 64;

  // LDS: K streams [0,32768): wave*8192 + buf*4096 ; V streams [32768,65536);
  // Ps [65536, 72704): wave*1792 (16 q-rows x 56 shorts).
  // Merge reuse of [0,65536): ObA/ObB (64c x 68 f32) + lbA/lbB.
  __shared__ __align__(16) unsigned char smem[72704];
  unsigned short* Pw = (unsigned short*)(smem + 65536 + wave * 1792);
  float* ObA = (float*)smem;
  float* ObB = (float*)(smem + 17408);
  float* lbA = (float*)(smem + 34816);
  float* lbB = (float*)(smem + 35072);

  const short8 vones = {(short)0x3F80, (short)0x3F80, (short)0x3F80, (short)0x3F80,
                        (short)0x3F80, (short)0x3F80, (short)0x3F80, (short)0x3F80};

  // Q B-fragments: 4 r-groups x 2 channel halves
  short8 qf[4][2];
#pragma unroll
  for (int r = 0; r < 4; r++)
#pragma unroll
    for (int h = 0; h < 2; h++)
      qf[r][h] = *reinterpret_cast<const short8*>(
          Qb + (size_t)(q_base + r * 16 + l15) * HD_ + h * 32 + quad * 8);

  // O^T accumulators: oa[r][ct] rows c=16ct+4quad+i, col q=r*16+l15; la = l
  f32x4 oa[4][4], la[4];
#pragma unroll
  for (int r = 0; r < 4; r++) {
    la[r] = (f32x4){0.f, 0.f, 0.f, 0.f};
#pragma unroll
    for (int ct = 0; ct < 4; ct++) oa[r][ct] = (f32x4){0.f, 0.f, 0.f, 0.f};
  }

  int i8 = lane >> 3, e8 = lane & 7;   // K staging geometry (8 rows x 8 granules)
  int r16 = lane >> 2, e4 = lane & 3;  // V staging geometry (16 rows x 4 granules)
  int kperm = (e8 ^ i8) * 8;
  int vperm = (e4 ^ ((r16 >> 1) & 3)) * 8;

  auto stage = [&](int kt2, int buf) {
    int m0 = khalf * 2048 + kt2 * 32;
    unsigned short* Kd = (unsigned short*)(smem + wave * 8192 + buf * 4096);
    unsigned short* Vd = (unsigned short*)(smem + 32768 + wave * 8192 + buf * 4096);
#pragma unroll
    for (int cc = 0; cc < 4; cc++) {
      dma16(Kb + (size_t)(m0 + cc * 8 + i8) * HD_ + kperm, Kd + cc * 512);
      dma16(Vb + (size_t)(cc * 16 + r16) * N_ + m0 + vperm, Vd + cc * 512);
    }
  };

  stage(0, 0);

#pragma unroll 1
  for (int kt = 0; kt < 64; kt++) {
    int buf = kt & 1;
    asm volatile("s_waitcnt vmcnt(0)" ::: "memory");  // own stage(kt) landed
    if (kt + 1 < 64) stage(kt + 1, buf ^ 1);          // full-iter DMA lead time

    const unsigned short* Kw = (const unsigned short*)(smem + wave * 8192 + buf * 4096);
    const unsigned short* Vw = (const unsigned short*)(smem + 32768 + wave * 8192 + buf * 4096);

    // K A-frags: key = tt*16+l15 (tt 0..1), ch granule swizzled by row&7
    short8 kf[2][2];
#pragma unroll
    for (int tt = 0; tt < 2; tt++)
#pragma unroll
      for (int kh = 0; kh < 2; kh++)
        kf[tt][kh] = *reinterpret_cast<const short8*>(
            &Kw[(tt * 16 + l15) * 64 + (((kh * 4 + quad) ^ l7) * 8)]);
    // V A-frags: c = ct*16+l15, key granule = quad swizzled by (l15>>1)&3
    short8 vf[4];
#pragma unroll
    for (int ct = 0; ct < 4; ct++)
      vf[ct] = *reinterpret_cast<const short8*>(
          &Vw[(ct * 16 + l15) * 32 + ((quad ^ ((l15 >> 1) & 3)) * 8)]);

#pragma unroll
    for (int r = 0; r < 4; r++) {
      f32x4 s0, s1;
      {
        f32x4 z = (f32x4){0.f, 0.f, 0.f, 0.f};
        z  = __builtin_amdgcn_mfma_f32_16x16x32_bf16(kf[0][0], qf[r][0], z, 0, 0, 0);
        s0 = __builtin_amdgcn_mfma_f32_16x16x32_bf16(kf[0][1], qf[r][1], z, 0, 0, 0);
      }
      {
        f32x4 z = (f32x4){0.f, 0.f, 0.f, 0.f};
        z  = __builtin_amdgcn_mfma_f32_16x16x32_bf16(kf[1][0], qf[r][0], z, 0, 0, 0);
        s1 = __builtin_amdgcn_mfma_f32_16x16x32_bf16(kf[1][1], qf[r][1], z, 0, 0, 0);
      }
      union { unsigned u2[2]; us4 v; } w0, w1;
      w0.u2[0] = pkbf2(__builtin_amdgcn_exp2f(s0[0]), __builtin_amdgcn_exp2f(s0[1]));
      w0.u2[1] = pkbf2(__builtin_amdgcn_exp2f(s0[2]), __builtin_amdgcn_exp2f(s0[3]));
      w1.u2[0] = pkbf2(__builtin_amdgcn_exp2f(s1[0]), __builtin_amdgcn_exp2f(s1[1]));
      w1.u2[1] = pkbf2(__builtin_amdgcn_exp2f(s1[2]), __builtin_amdgcn_exp2f(s1[3]));
      *reinterpret_cast<us4*>(&Pw[l15 * 56 + quad * 4]) = w0.v;       // keys 0..15
      *reinterpret_cast<us4*>(&Pw[l15 * 56 + 16 + quad * 4]) = w1.v;  // keys 16..31
      short8 pf = *reinterpret_cast<const short8*>(&Pw[l15 * 56 + quad * 8]);
#pragma unroll
      for (int ct = 0; ct < 4; ct++)
        oa[r][ct] = __builtin_amdgcn_mfma_f32_16x16x32_bf16(vf[ct], pf, oa[r][ct], 0, 0, 0);
      la[r] = __builtin_amdgcn_mfma_f32_16x16x32_bf16(vones, pf, la[r], 0, 0, 0);
    }
  }

  // ---- exact key-half merge (plain O/l add; khalf partners share qsub) ----
  __syncthreads();
  if (khalf == 1) {
    float* Ob = (qsub == 0) ? ObA : ObB;
    float* lb = (qsub == 0) ? lbA : lbB;
#pragma unroll
    for (int r = 0; r < 4; r++) {
#pragma unroll
      for (int ct = 0; ct < 4; ct++)
#pragma unroll
        for (int i = 0; i < 4; i++)
          Ob[(ct * 16 + quad * 4 + i) * 68 + r * 16 + l15] = oa[r][ct][i];
      if (quad == 0) lb[r * 16 + l15] = la[r][0];
    }
  }
  __syncthreads();
  if (khalf == 0) {
    const float* Ob = (qsub == 0) ? ObA : ObB;
    const float* lb = (qsub == 0) ? lbA : lbB;
#pragma unroll
    for (int r = 0; r < 4; r++) {
      float inv = 1.0f / (la[r][0] + lb[r * 16 + l15]);
      int n = q_base + r * 16 + l15;
#pragma unroll
      for (int ct = 0; ct < 4; ct++) {
        const float* ob = &Ob[(ct * 16 + quad * 4) * 68 + r * 16 + l15];
        union { unsigned u2[2]; us4 v; } w;
        w.u2[0] = pkbf2((oa[r][ct][0] + ob[0]) * inv, (oa[r][ct][1] + ob[68]) * inv);
        w.u2[1] = pkbf2((oa[r][ct][2] + ob[136]) * inv, (oa[r][ct][3] + ob[204]) * inv);
        *reinterpret_cast<us4*>(
            aoT + ((size_t)(b * N_ + n)) * C_ + head * HD_ + ct * 16 + quad * 4) = w.v;
      }
    }
  }
}

// ---------------------------------------------------------------------------
// Kernel 7: proj GEMM + bias + residual (R4 version). aoT tile LDS-staged.
// ---------------------------------------------------------------------------
__global__ __launch_bounds__(256) void proj_gemm(
    const unsigned short* __restrict__ aoT, const unsigned short* __restrict__ wp,
    const float* __restrict__ pb, const float* __restrict__ x,
    float* __restrict__ out) {
  int nt = blockIdx.x, ot = blockIdx.y, b = blockIdx.z;
  int t = threadIdx.x;
  int wave = t >> 6, lane = t & 63, l15 = lane & 15, quad = lane >> 4, l7 = l15 & 7;
  int o_base = ot * 64 + wave * 16;

  __shared__ __align__(16) unsigned short sh[64 * C_];
  {
    int row0 = wave * 2 + (lane >> 5);
    int col8 = lane & 31;
    int src8 = (col8 & 24) | ((col8 & 7) ^ (row0 & 7));
    const unsigned short* gsrc = aoT + ((size_t)(b * N_ + nt * 64 + row0)) * C_ + src8 * 8;
#pragma unroll
    for (int it = 0; it < 8; it++)
      dma16(gsrc + (size_t)it * 8 * C_, sh + (it * 8 + wave * 2) * C_);
  }

  f32x4 acc[4];
#pragma unroll
  for (int tt = 0; tt < 4; tt++) acc[tt] = (f32x4){0.f, 0.f, 0.f, 0.f};

  const short8* arow = reinterpret_cast<const short8*>(wp + (size_t)(o_base + l15) * C_);

  asm volatile("s_waitcnt vmcnt(0)" ::: "memory");
  __syncthreads();

#pragma unroll
  for (int kk = 0; kk < 8; kk++) {
    short8 a = arow[kk * 4 + quad];
    int g = kk * 4 + quad;
    int col8 = (g & 24) | ((g & 7) ^ l7);
#pragma unroll
    for (int tt = 0; tt < 4; tt++) {
      short8 bf = *reinterpret_cast<const short8*>(&sh[(tt * 16 + l15) * C_ + col8 * 8]);
      acc[tt] = __builtin_amdgcn_mfma_f32_16x16x32_bf16(a, bf, acc[tt], 0, 0, 0);
    }
  }
#pragma unroll
  for (int tt = 0; tt < 4; tt++) {
    int n = nt * 64 + tt * 16 + l15;
#pragma unroll
    for (int i = 0; i < 4; i++) {
      int o = o_base + quad * 4 + i;
      size_t idx = ((size_t)(b * C_ + o)) * N_ + n;
      out[idx] = acc[tt][i] + pb[o] + x[idx];
    }
  }
}

// ---------------------------------------------------------------------------
extern "C" void kernel_launch(void* const* d_in, const int* in_sizes, int n_in,
                              void* d_out, int out_size, void* d_ws, size_t ws_size,
                              hipStream_t stream) {
  const float* x      = (const float*)d_in[0];
  const float* norm_w = (const float*)d_in[1];
  const float* norm_b = (const float*)d_in[2];
  const float* qkv_w  = (const float*)d_in[3];
  const float* qkv_b  = (const float*)d_in[4];
  const float* proj_w = (const float*)d_in[5];
  const float* proj_b = (const float*)d_in[6];
  float* out = (float*)d_out;

  char* ws = (char*)d_ws;
  size_t off = 0;
  auto alloc = [&](size_t bytes) { size_t o = off; off = (off + bytes + 255) & ~(size_t)255; return o; };
  size_t off_partial = alloc(512 * 2 * sizeof(float));
  size_t off_stats   = alloc(32 * 2 * sizeof(float));
  size_t off_wq      = alloc((size_t)768 * 256 * 2);
  size_t off_wp      = alloc((size_t)256 * 256 * 2);
  size_t off_hT      = alloc((size_t)B_ * N_ * C_ * 2);
  size_t off_Qt      = alloc((size_t)B_ * NH_ * N_ * HD_ * 2);
  size_t off_Kt      = alloc((size_t)B_ * NH_ * N_ * HD_ * 2);
  size_t off_V       = alloc((size_t)B_ * NH_ * HD_ * N_ * 2);
  size_t off_aoT     = alloc((size_t)B_ * N_ * C_ * 2);

  float* partial = (float*)(ws + off_partial);
  float* stats   = (float*)(ws + off_stats);
  unsigned short* wq  = (unsigned short*)(ws + off_wq);
  unsigned short* wp  = (unsigned short*)(ws + off_wp);
  unsigned short* hT  = (unsigned short*)(ws + off_hT);
  unsigned short* Qt  = (unsigned short*)(ws + off_Qt);
  unsigned short* Kt  = (unsigned short*)(ws + off_Kt);
  unsigned short* V   = (unsigned short*)(ws + off_V);
  unsigned short* aoT = (unsigned short*)(ws + off_aoT);

  cvt_weights<<<768, 256, 0, stream>>>(qkv_w, proj_w, wq, wp);
  gn_partial<<<512, 256, 0, stream>>>(x, partial);
  gn_finalize<<<1, 64, 0, stream>>>(partial, stats);
  gn_apply<<<dim3(64, 8, 4), 256, 0, stream>>>(x, norm_w, norm_b, stats, hT);
  qkv_gemm<<<dim3(64, 12, 4), 256, 0, stream>>>(hT, wq, qkv_b, Qt, Kt, V);
  flash_attn<<<512, 256, 0, stream>>>(Qt, Kt, V, aoT);
  proj_gemm<<<dim3(64, 4, 4), 256, 0, stream>>>(aoT, wp, proj_b, x, out);
}

// Round 9
// 200.779 us; speedup vs baseline: 1.1111x; 1.0432x over previous
//
#include <hip/hip_runtime.h>
#include <hip/hip_bf16.h>
#include <stdint.h>

// ---------------------------------------------------------------------------
// SelfAttention2d: B=4, C=256, H=W=64 (N=4096), NUM_HEADS=4 (hd=64), GROUPS=8
// R8 (= R7 with type-name fix): flash v7 — R4 structure (shared double-
//     buffered K/V streams, 1 barrier/iter, grid 512) + P-in-register PV:
//     S^T C-layout from 16x16x32 is bit-identical to the 16x16x16 B-operand
//     layout, so exp2(S) feeds PV MFMA directly from VGPRs. No P LDS traffic.
//     qkv/proj/gn kernels = R4 versions (best known).
// ---------------------------------------------------------------------------

#define B_  4
#define C_  256
#define N_  4096
#define NH_ 4
#define HD_ 64
#define G_  8
#define CPG_ 32
#define GRP_ELEMS (CPG_ * N_)

typedef __attribute__((ext_vector_type(8))) short short8;
typedef __attribute__((ext_vector_type(4))) short bf4;     // renamed: avoid HIP short4
typedef __attribute__((ext_vector_type(4))) float f32x4;
typedef __attribute__((ext_vector_type(4))) unsigned short us4;

__device__ __forceinline__ unsigned short f2bf(float f) {
  union { float f; unsigned u; } v; v.f = f;
  unsigned r = v.u + 0x7FFFu + ((v.u >> 16) & 1u);
  return (unsigned short)(r >> 16);
}

// packed fp32x2 -> bf16x2 (v_cvt_pk_bf16_f32 on gfx950)
__device__ __forceinline__ unsigned pkbf2(float a, float b) {
  __hip_bfloat162 h = __float22bfloat162_rn(make_float2(a, b));
  unsigned r; __builtin_memcpy(&r, &h, sizeof(r)); return r;
}

// async 16B/lane global->LDS DMA; LDS dest = uniform base + lane*16
__device__ __forceinline__ void dma16(const unsigned short* g, unsigned short* l) {
  __builtin_amdgcn_global_load_lds(
      (const __attribute__((address_space(1))) unsigned int*)(g),
      (__attribute__((address_space(3))) unsigned int*)(l), 16, 0, 0);
}

// ---------------------------------------------------------------------------
// Kernel 1: convert qkv_w (768x256) and proj_w (256x256) fp32 -> bf16
// ---------------------------------------------------------------------------
__global__ void cvt_weights(const float* __restrict__ qkvw,
                            const float* __restrict__ projw,
                            unsigned short* __restrict__ wq,
                            unsigned short* __restrict__ wp) {
  int i = blockIdx.x * 256 + threadIdx.x;
  if (i < 768 * 256) wq[i] = f2bf(qkvw[i]);
  if (i < 256 * 256) wp[i] = f2bf(projw[i]);
}

// ---------------------------------------------------------------------------
// Kernel 2: groupnorm partial sums. 512 blocks = (b,g,slice16), 256 threads.
// ---------------------------------------------------------------------------
__global__ void gn_partial(const float* __restrict__ x, float* __restrict__ partial) {
  int idx = blockIdx.x;
  int slice = idx & 15, g = (idx >> 4) & 7, b = idx >> 7;
  int t = threadIdx.x;
  const float* base = x + (size_t)(b * C_ + g * CPG_) * N_ + slice * 256;
  float s = 0.f, sq = 0.f;
#pragma unroll
  for (int cc = 0; cc < CPG_; cc++) {
    float v = base[(size_t)cc * N_ + t];
    s += v; sq += v * v;
  }
#pragma unroll
  for (int off = 32; off; off >>= 1) {
    s  += __shfl_down(s,  off, 64);
    sq += __shfl_down(sq, off, 64);
  }
  __shared__ float ls[8];
  int wave = t >> 6, lane = t & 63;
  if (lane == 0) { ls[wave * 2] = s; ls[wave * 2 + 1] = sq; }
  __syncthreads();
  if (t == 0) {
    float S = ls[0] + ls[2] + ls[4] + ls[6];
    float SQ = ls[1] + ls[3] + ls[5] + ls[7];
    partial[idx * 2] = S; partial[idx * 2 + 1] = SQ;
  }
}

// ---------------------------------------------------------------------------
// Kernel 3: finalize stats. 32 groups, stats[g] = {mean, rstd}
// ---------------------------------------------------------------------------
__global__ void gn_finalize(const float* __restrict__ partial, float* __restrict__ stats) {
  int t = threadIdx.x;
  if (t < 32) {
    float s = 0.f, sq = 0.f;
    for (int i = 0; i < 16; i++) {
      s  += partial[(t * 16 + i) * 2];
      sq += partial[(t * 16 + i) * 2 + 1];
    }
    const float inv = 1.0f / (float)GRP_ELEMS;
    float mean = s * inv;
    float var = sq * inv - mean * mean;
    stats[t * 2] = mean;
    stats[t * 2 + 1] = rsqrtf(var + 1e-5f);
  }
}

// ---------------------------------------------------------------------------
// Kernel 4: normalize + transpose. x (B,C,N) fp32 -> hT (B,N,C) bf16.
// ---------------------------------------------------------------------------
__global__ void gn_apply(const float* __restrict__ x,
                         const float* __restrict__ nw, const float* __restrict__ nb,
                         const float* __restrict__ stats, unsigned short* __restrict__ hT) {
  int nt = blockIdx.x, ct = blockIdx.y, b = blockIdx.z;
  __shared__ unsigned short tile[32][72];
  int t = threadIdx.x;
  int n_loc = t & 63, c_loc = t >> 6;
  float mean = stats[(b * G_ + ct) * 2];
  float rstd = stats[(b * G_ + ct) * 2 + 1];
  const float* xb = x + (size_t)(b * C_ + ct * CPG_) * N_ + nt * 64;
#pragma unroll
  for (int rr = 0; rr < 8; rr++) {
    int cc = rr * 4 + c_loc;
    int c = ct * CPG_ + cc;
    float v = xb[(size_t)cc * N_ + n_loc];
    v = (v - mean) * rstd * nw[c] + nb[c];
    tile[cc][n_loc] = f2bf(v);
  }
  __syncthreads();
  int c2 = t & 31, n2 = t >> 5;
  unsigned short* out = hT + ((size_t)(b * N_ + nt * 64)) * C_ + ct * CPG_ + c2;
#pragma unroll
  for (int pass = 0; pass < 8; pass++) {
    int n = pass * 8 + n2;
    out[(size_t)n * C_] = tile[c2][n];
  }
}

// ---------------------------------------------------------------------------
// Kernel 5: qkv GEMM (R4 version). D[o][n] = sum_c Wqkv[o][c]*hT[n][c]+bias.
// ---------------------------------------------------------------------------
__global__ __launch_bounds__(256) void qkv_gemm(
    const unsigned short* __restrict__ hT, const unsigned short* __restrict__ wq,
    const float* __restrict__ qb,
    unsigned short* __restrict__ Qt, unsigned short* __restrict__ Kt,
    unsigned short* __restrict__ V) {
  int nt = blockIdx.x, ot = blockIdx.y, b = blockIdx.z;
  int t = threadIdx.x;
  int wave = t >> 6, lane = t & 63, l15 = lane & 15, quad = lane >> 4, l7 = l15 & 7;
  int o_base = ot * 64 + wave * 16;

  __shared__ __align__(16) unsigned short sh[64 * C_];
  {
    int row0 = wave * 2 + (lane >> 5);
    int col8 = lane & 31;
    int src8 = (col8 & 24) | ((col8 & 7) ^ (row0 & 7));
    const unsigned short* gsrc = hT + ((size_t)(b * N_ + nt * 64 + row0)) * C_ + src8 * 8;
#pragma unroll
    for (int it = 0; it < 8; it++)
      dma16(gsrc + (size_t)it * 8 * C_, sh + (it * 8 + wave * 2) * C_);
  }

  f32x4 acc[4];
#pragma unroll
  for (int tt = 0; tt < 4; tt++) acc[tt] = (f32x4){0.f, 0.f, 0.f, 0.f};

  const short8* arow = reinterpret_cast<const short8*>(wq + (size_t)(o_base + l15) * C_);

  asm volatile("s_waitcnt vmcnt(0)" ::: "memory");
  __syncthreads();

#pragma unroll
  for (int kk = 0; kk < 8; kk++) {
    short8 a = arow[kk * 4 + quad];
    int g = kk * 4 + quad;
    int col8 = (g & 24) | ((g & 7) ^ l7);
#pragma unroll
    for (int tt = 0; tt < 4; tt++) {
      short8 bf = *reinterpret_cast<const short8*>(&sh[(tt * 16 + l15) * C_ + col8 * 8]);
      acc[tt] = __builtin_amdgcn_mfma_f32_16x16x32_bf16(a, bf, acc[tt], 0, 0, 0);
    }
  }

  int sec = ot >> 2, head = ot & 3;
  int cw = wave * 16 + quad * 4;
  int bh = b * NH_ + head;
  const float SC = 0.125f * 1.44269504088896340736f;  // 1/sqrt(hd) * log2(e)

  if (sec == 0) {
#pragma unroll
    for (int tt = 0; tt < 4; tt++) {
      int n = nt * 64 + tt * 16 + l15;
      us4 pk;
#pragma unroll
      for (int i = 0; i < 4; i++)
        pk[i] = f2bf((acc[tt][i] + qb[ot * 64 + cw + i]) * SC);
      *reinterpret_cast<us4*>(Qt + ((size_t)bh * N_ + n) * HD_ + cw) = pk;
    }
  } else if (sec == 1) {
#pragma unroll
    for (int tt = 0; tt < 4; tt++) {
      int n = nt * 64 + tt * 16 + l15;
      us4 pk;
#pragma unroll
      for (int i = 0; i < 4; i++)
        pk[i] = f2bf(acc[tt][i] + qb[ot * 64 + cw + i]);
      *reinterpret_cast<us4*>(Kt + ((size_t)bh * N_ + n) * HD_ + cw) = pk;
    }
  } else {
#pragma unroll
    for (int tt = 0; tt < 4; tt++) {
      int n = nt * 64 + tt * 16 + l15;
#pragma unroll
      for (int i = 0; i < 4; i++)
        V[((size_t)bh * HD_ + cw + i) * N_ + n] = f2bf(acc[tt][i] + qb[ot * 64 + cw + i]);
    }
  }
}

// ---------------------------------------------------------------------------
// Kernel 6: flash attention v7.
// Grid 512 = (bh = blockIdx&15, qt = blockIdx>>4), 4 waves =
// qsub(wave>>1) x khalf(wave&1). Wave: 64 q x 2048 keys, 32 iters of 64 keys.
// Shared double-buffered K/V streams per khalf (2 waves co-stage), one
// barrier/iter. S^T via 16x16x32; PV via 16x16x16 with P passed in REGISTERS
// (S^T C-layout == 16x16x16 B-operand layout). No P LDS traffic.
// ---------------------------------------------------------------------------
__global__ __launch_bounds__(256, 2) void flash_attn(
    const unsigned short* __restrict__ Qt, const unsigned short* __restrict__ Kt,
    const unsigned short* __restrict__ Vv, unsigned short* __restrict__ aoT) {
  int bh = blockIdx.x & 15, qt = blockIdx.x >> 4;
  int b = bh >> 2, head = bh & 3;
  int t = threadIdx.x;
  int wave = t >> 6, lane = t & 63, l15 = lane & 15, quad = lane >> 4;
  int l7 = l15 & 7;
  int qsub = wave >> 1, khalf = wave & 1;

  const unsigned short* Qb = Qt + (size_t)bh * N_ * HD_;
  const unsigned short* Kb = Kt + (size_t)bh * N_ * HD_;
  const unsigned short* Vb = Vv + (size_t)bh * HD_ * N_;
  int q_base = qt * 128 + qsub * 64;

  // LDS: K streams [0,32768): khalf*16384 + buf*8192 ; V [32768,65536).
  // Merge overlay: ObA/ObB (64c x 68 f32) + lbA/lbB.
  __shared__ __align__(16) unsigned char smem[65536];
  float* ObA = (float*)smem;
  float* ObB = (float*)(smem + 17408);
  float* lbA = (float*)(smem + 34816);
  float* lbB = (float*)(smem + 35072);

  const bf4 vones4 = {(short)0x3F80, (short)0x3F80, (short)0x3F80, (short)0x3F80};

  // Q B-fragments: 4 r-groups x 2 channel halves
  short8 qf[4][2];
#pragma unroll
  for (int r = 0; r < 4; r++)
#pragma unroll
    for (int h = 0; h < 2; h++)
      qf[r][h] = *reinterpret_cast<const short8*>(
          Qb + (size_t)(q_base + r * 16 + l15) * HD_ + h * 32 + quad * 8);

  // O^T accumulators: oa[r][ct] rows c=16ct+4quad+i, col q=r*16+l15; la = l
  f32x4 oa[4][4], la[4];
#pragma unroll
  for (int r = 0; r < 4; r++) {
    la[r] = (f32x4){0.f, 0.f, 0.f, 0.f};
#pragma unroll
    for (int ct = 0; ct < 4; ct++) oa[r][ct] = (f32x4){0.f, 0.f, 0.f, 0.f};
  }

  int i8 = lane >> 3, e8 = lane & 7;
  int perm = (e8 ^ i8) * 8;   // XOR swizzle of 16B granules (8 elements)
  auto stage = [&](int kt2, int buf) {
    int m0 = khalf * 2048 + kt2 * 64;
    unsigned short* Kd = (unsigned short*)(smem + khalf * 16384 + buf * 8192);
    unsigned short* Vd = (unsigned short*)(smem + 32768 + khalf * 16384 + buf * 8192);
#pragma unroll
    for (int cc = 0; cc < 4; cc++) {
      int c = qsub * 4 + cc;   // 2 waves co-stage the 8 chunks of their stream
      dma16(Kb + (size_t)(m0 + c * 8 + i8) * HD_ + perm, Kd + c * 512);
      dma16(Vb + (size_t)(c * 8 + i8) * N_ + m0 + perm, Vd + c * 512);
    }
  };

  stage(0, 0);

#pragma unroll 1
  for (int kt = 0; kt < 32; kt++) {
    int buf = kt & 1;
    asm volatile("s_waitcnt vmcnt(0)" ::: "memory");  // own half of tile landed
    __builtin_amdgcn_s_barrier();                      // partner's half landed
    if (kt + 1 < 32) stage(kt + 1, buf ^ 1);

    const unsigned short* Kw = (const unsigned short*)(smem + khalf * 16384 + buf * 8192);
    const unsigned short* Vw = (const unsigned short*)(smem + 32768 + khalf * 16384 + buf * 8192);

    // K A-frags (K=32): key = tt*16+l15, 16B ch-granule swizzled by l7
    short8 kf[4][2];
#pragma unroll
    for (int tt = 0; tt < 4; tt++)
#pragma unroll
      for (int kh = 0; kh < 2; kh++)
        kf[tt][kh] = *reinterpret_cast<const short8*>(
            &Kw[(tt * 16 + l15) * 64 + (((kh * 4 + quad) ^ l7) * 8)]);

    // V A-frags (K=16): c = ct*16+l15, keys tt*16+quad*4..+3 (b64, swizzled)
    bf4 vf[4][4];
#pragma unroll
    for (int ct = 0; ct < 4; ct++)
#pragma unroll
      for (int tt = 0; tt < 4; tt++)
        vf[ct][tt] = *reinterpret_cast<const bf4*>(
            &Vw[(ct * 16 + l15) * 64 + (((tt * 2 + (quad >> 1)) ^ l7) * 8) + (quad & 1) * 4]);

#pragma unroll
    for (int r = 0; r < 4; r++) {
      // S^T: C-layout (row=key=tt*16+quad*4+i, col=q=l15)
      f32x4 s[4];
#pragma unroll
      for (int tt = 0; tt < 4; tt++) {
        f32x4 z = (f32x4){0.f, 0.f, 0.f, 0.f};
        z = __builtin_amdgcn_mfma_f32_16x16x32_bf16(kf[tt][0], qf[r][0], z, 0, 0, 0);
        s[tt] = __builtin_amdgcn_mfma_f32_16x16x32_bf16(kf[tt][1], qf[r][1], z, 0, 0, 0);
      }
      // P = exp2(S) packed in-register == 16x16x16 B-operand fragment
#pragma unroll
      for (int tt = 0; tt < 4; tt++) {
        union { unsigned u2[2]; bf4 v; } w;
        w.u2[0] = pkbf2(__builtin_amdgcn_exp2f(s[tt][0]), __builtin_amdgcn_exp2f(s[tt][1]));
        w.u2[1] = pkbf2(__builtin_amdgcn_exp2f(s[tt][2]), __builtin_amdgcn_exp2f(s[tt][3]));
        bf4 pf = w.v;
#pragma unroll
        for (int ct = 0; ct < 4; ct++)
          oa[r][ct] = __builtin_amdgcn_mfma_f32_16x16x16bf16_1k(vf[ct][tt], pf, oa[r][ct], 0, 0, 0);
        la[r] = __builtin_amdgcn_mfma_f32_16x16x16bf16_1k(vones4, pf, la[r], 0, 0, 0);
      }
    }
  }

  // ---- exact key-half merge (plain O/l add; khalf partners share qsub) ----
  __syncthreads();
  if (khalf == 1) {
    float* Ob = (qsub == 0) ? ObA : ObB;
    float* lb = (qsub == 0) ? lbA : lbB;
#pragma unroll
    for (int r = 0; r < 4; r++) {
#pragma unroll
      for (int ct = 0; ct < 4; ct++)
#pragma unroll
        for (int i = 0; i < 4; i++)
          Ob[(ct * 16 + quad * 4 + i) * 68 + r * 16 + l15] = oa[r][ct][i];
      if (quad == 0) lb[r * 16 + l15] = la[r][0];
    }
  }
  __syncthreads();
  if (khalf == 0) {
    const float* Ob = (qsub == 0) ? ObA : ObB;
    const float* lb = (qsub == 0) ? lbA : lbB;
#pragma unroll
    for (int r = 0; r < 4; r++) {
      float inv = 1.0f / (la[r][0] + lb[r * 16 + l15]);
      int n = q_base + r * 16 + l15;
#pragma unroll
      for (int ct = 0; ct < 4; ct++) {
        const float* ob = &Ob[(ct * 16 + quad * 4) * 68 + r * 16 + l15];
        union { unsigned u2[2]; us4 v; } w;
        w.u2[0] = pkbf2((oa[r][ct][0] + ob[0]) * inv, (oa[r][ct][1] + ob[68]) * inv);
        w.u2[1] = pkbf2((oa[r][ct][2] + ob[136]) * inv, (oa[r][ct][3] + ob[204]) * inv);
        *reinterpret_cast<us4*>(
            aoT + ((size_t)(b * N_ + n)) * C_ + head * HD_ + ct * 16 + quad * 4) = w.v;
      }
    }
  }
}

// ---------------------------------------------------------------------------
// Kernel 7: proj GEMM + bias + residual (R4 version). aoT tile LDS-staged.
// ---------------------------------------------------------------------------
__global__ __launch_bounds__(256) void proj_gemm(
    const unsigned short* __restrict__ aoT, const unsigned short* __restrict__ wp,
    const float* __restrict__ pb, const float* __restrict__ x,
    float* __restrict__ out) {
  int nt = blockIdx.x, ot = blockIdx.y, b = blockIdx.z;
  int t = threadIdx.x;
  int wave = t >> 6, lane = t & 63, l15 = lane & 15, quad = lane >> 4, l7 = l15 & 7;
  int o_base = ot * 64 + wave * 16;

  __shared__ __align__(16) unsigned short sh[64 * C_];
  {
    int row0 = wave * 2 + (lane >> 5);
    int col8 = lane & 31;
    int src8 = (col8 & 24) | ((col8 & 7) ^ (row0 & 7));
    const unsigned short* gsrc = aoT + ((size_t)(b * N_ + nt * 64 + row0)) * C_ + src8 * 8;
#pragma unroll
    for (int it = 0; it < 8; it++)
      dma16(gsrc + (size_t)it * 8 * C_, sh + (it * 8 + wave * 2) * C_);
  }

  f32x4 acc[4];
#pragma unroll
  for (int tt = 0; tt < 4; tt++) acc[tt] = (f32x4){0.f, 0.f, 0.f, 0.f};

  const short8* arow = reinterpret_cast<const short8*>(wp + (size_t)(o_base + l15) * C_);

  asm volatile("s_waitcnt vmcnt(0)" ::: "memory");
  __syncthreads();

#pragma unroll
  for (int kk = 0; kk < 8; kk++) {
    short8 a = arow[kk * 4 + quad];
    int g = kk * 4 + quad;
    int col8 = (g & 24) | ((g & 7) ^ l7);
#pragma unroll
    for (int tt = 0; tt < 4; tt++) {
      short8 bf = *reinterpret_cast<const short8*>(&sh[(tt * 16 + l15) * C_ + col8 * 8]);
      acc[tt] = __builtin_amdgcn_mfma_f32_16x16x32_bf16(a, bf, acc[tt], 0, 0, 0);
    }
  }
#pragma unroll
  for (int tt = 0; tt < 4; tt++) {
    int n = nt * 64 + tt * 16 + l15;
#pragma unroll
    for (int i = 0; i < 4; i++) {
      int o = o_base + quad * 4 + i;
      size_t idx = ((size_t)(b * C_ + o)) * N_ + n;
      out[idx] = acc[tt][i] + pb[o] + x[idx];
    }
  }
}

// ---------------------------------------------------------------------------
extern "C" void kernel_launch(void* const* d_in, const int* in_sizes, int n_in,
                              void* d_out, int out_size, void* d_ws, size_t ws_size,
                              hipStream_t stream) {
  const float* x      = (const float*)d_in[0];
  const float* norm_w = (const float*)d_in[1];
  const float* norm_b = (const float*)d_in[2];
  const float* qkv_w  = (const float*)d_in[3];
  const float* qkv_b  = (const float*)d_in[4];
  const float* proj_w = (const float*)d_in[5];
  const float* proj_b = (const float*)d_in[6];
  float* out = (float*)d_out;

  char* ws = (char*)d_ws;
  size_t off = 0;
  auto alloc = [&](size_t bytes) { size_t o = off; off = (off + bytes + 255) & ~(size_t)255; return o; };
  size_t off_partial = alloc(512 * 2 * sizeof(float));
  size_t off_stats   = alloc(32 * 2 * sizeof(float));
  size_t off_wq      = alloc((size_t)768 * 256 * 2);
  size_t off_wp      = alloc((size_t)256 * 256 * 2);
  size_t off_hT      = alloc((size_t)B_ * N_ * C_ * 2);
  size_t off_Qt      = alloc((size_t)B_ * NH_ * N_ * HD_ * 2);
  size_t off_Kt      = alloc((size_t)B_ * NH_ * N_ * HD_ * 2);
  size_t off_V       = alloc((size_t)B_ * NH_ * HD_ * N_ * 2);
  size_t off_aoT     = alloc((size_t)B_ * N_ * C_ * 2);

  float* partial = (float*)(ws + off_partial);
  float* stats   = (float*)(ws + off_stats);
  unsigned short* wq  = (unsigned short*)(ws + off_wq);
  unsigned short* wp  = (unsigned short*)(ws + off_wp);
  unsigned short* hT  = (unsigned short*)(ws + off_hT);
  unsigned short* Qt  = (unsigned short*)(ws + off_Qt);
  unsigned short* Kt  = (unsigned short*)(ws + off_Kt);
  unsigned short* V   = (unsigned short*)(ws + off_V);
  unsigned short* aoT = (unsigned short*)(ws + off_aoT);

  cvt_weights<<<768, 256, 0, stream>>>(qkv_w, proj_w, wq, wp);
  gn_partial<<<512, 256, 0, stream>>>(x, partial);
  gn_finalize<<<1, 64, 0, stream>>>(partial, stats);
  gn_apply<<<dim3(64, 8, 4), 256, 0, stream>>>(x, norm_w, norm_b, stats, hT);
  qkv_gemm<<<dim3(64, 12, 4), 256, 0, stream>>>(hT, wq, qkv_b, Qt, Kt, V);
  flash_attn<<<512, 256, 0, stream>>>(Qt, Kt, V, aoT);
  proj_gemm<<<dim3(64, 4, 4), 256, 0, stream>>>(aoT, wp, proj_b, x, out);
}

// Round 10
// 193.596 us; speedup vs baseline: 1.1524x; 1.0371x over previous
//
#include <hip/hip_runtime.h>
#include <hip/hip_bf16.h>
#include <stdint.h>

// ---------------------------------------------------------------------------
// SelfAttention2d: B=4, C=256, H=W=64 (N=4096), NUM_HEADS=4 (hd=64), GROUPS=8
// R9: flash reverted to R4 (best known 99.5us). Non-flash consolidated:
//     - cvt_weights merged into gn_partial (one launch, block-range split)
//     - gn_finalize folded into gn_apply (in-wave shfl reduce of 16 partials)
//     - qkv/proj GEMMs widened to 128-n tiles (staging redundancy /2,
//       weight re-fetch /2, 2x MFMA per staged byte). 5 dispatches total.
// ---------------------------------------------------------------------------

#define B_  4
#define C_  256
#define N_  4096
#define NH_ 4
#define HD_ 64
#define G_  8
#define CPG_ 32
#define GRP_ELEMS (CPG_ * N_)

typedef __attribute__((ext_vector_type(8))) short short8;
typedef __attribute__((ext_vector_type(4))) float f32x4;
typedef __attribute__((ext_vector_type(4))) unsigned short us4;

__device__ __forceinline__ unsigned short f2bf(float f) {
  union { float f; unsigned u; } v; v.f = f;
  unsigned r = v.u + 0x7FFFu + ((v.u >> 16) & 1u);
  return (unsigned short)(r >> 16);
}

// packed fp32x2 -> bf16x2 (v_cvt_pk_bf16_f32 on gfx950)
__device__ __forceinline__ unsigned pkbf2(float a, float b) {
  __hip_bfloat162 h = __float22bfloat162_rn(make_float2(a, b));
  unsigned r; __builtin_memcpy(&r, &h, sizeof(r)); return r;
}

// async 16B/lane global->LDS DMA; LDS dest = uniform base + lane*16
__device__ __forceinline__ void dma16(const unsigned short* g, unsigned short* l) {
  __builtin_amdgcn_global_load_lds(
      (const __attribute__((address_space(1))) unsigned int*)(g),
      (__attribute__((address_space(3))) unsigned int*)(l), 16, 0, 0);
}

// ---------------------------------------------------------------------------
// Kernel 1: gn_partial (blocks 0..511) + weight conversion (blocks 512..1279).
// ---------------------------------------------------------------------------
__global__ void gn_partial_cvt(const float* __restrict__ x, float* __restrict__ partial,
                               const float* __restrict__ qkvw, const float* __restrict__ projw,
                               unsigned short* __restrict__ wq, unsigned short* __restrict__ wp) {
  __shared__ float ls[8];
  int t = threadIdx.x;
  if (blockIdx.x >= 512) {
    int i = (blockIdx.x - 512) * 256 + t;
    if (i < 768 * 256) wq[i] = f2bf(qkvw[i]);
    if (i < 256 * 256) wp[i] = f2bf(projw[i]);
    return;
  }
  int idx = blockIdx.x;
  int slice = idx & 15, g = (idx >> 4) & 7, b = idx >> 7;
  const float* base = x + (size_t)(b * C_ + g * CPG_) * N_ + slice * 256;
  float s = 0.f, sq = 0.f;
#pragma unroll
  for (int cc = 0; cc < CPG_; cc++) {
    float v = base[(size_t)cc * N_ + t];
    s += v; sq += v * v;
  }
#pragma unroll
  for (int off = 32; off; off >>= 1) {
    s  += __shfl_down(s,  off, 64);
    sq += __shfl_down(sq, off, 64);
  }
  int wave = t >> 6, lane = t & 63;
  if (lane == 0) { ls[wave * 2] = s; ls[wave * 2 + 1] = sq; }
  __syncthreads();
  if (t == 0) {
    float S = ls[0] + ls[2] + ls[4] + ls[6];
    float SQ = ls[1] + ls[3] + ls[5] + ls[7];
    partial[idx * 2] = S; partial[idx * 2 + 1] = SQ;
  }
}

// ---------------------------------------------------------------------------
// Kernel 2: normalize + transpose with INLINE stats (reduces 16 partials
// per group in-wave). x (B,C,N) fp32 -> hT (B,N,C) bf16.
// ---------------------------------------------------------------------------
__global__ void gn_apply(const float* __restrict__ x,
                         const float* __restrict__ nw, const float* __restrict__ nb,
                         const float* __restrict__ partial, unsigned short* __restrict__ hT) {
  int nt = blockIdx.x, ct = blockIdx.y, b = blockIdx.z;
  __shared__ unsigned short tile[32][72];
  int t = threadIdx.x;
  int lane = t & 63;
  // inline finalize: each wave reduces this group's 16 partial pairs
  int grp = b * G_ + ct;
  float s = 0.f, sq = 0.f;
  if (lane < 16) {
    s  = partial[(grp * 16 + lane) * 2];
    sq = partial[(grp * 16 + lane) * 2 + 1];
  }
#pragma unroll
  for (int off = 8; off; off >>= 1) {
    s  += __shfl_down(s,  off, 64);
    sq += __shfl_down(sq, off, 64);
  }
  s  = __shfl(s,  0, 64);
  sq = __shfl(sq, 0, 64);
  const float inv = 1.0f / (float)GRP_ELEMS;
  float mean = s * inv;
  float rstd = rsqrtf(sq * inv - mean * mean + 1e-5f);

  int n_loc = t & 63, c_loc = t >> 6;
  const float* xb = x + (size_t)(b * C_ + ct * CPG_) * N_ + nt * 64;
#pragma unroll
  for (int rr = 0; rr < 8; rr++) {
    int cc = rr * 4 + c_loc;
    int c = ct * CPG_ + cc;
    float v = xb[(size_t)cc * N_ + n_loc];
    v = (v - mean) * rstd * nw[c] + nb[c];
    tile[cc][n_loc] = f2bf(v);
  }
  __syncthreads();
  int c2 = t & 31, n2 = t >> 5;
  unsigned short* out = hT + ((size_t)(b * N_ + nt * 64)) * C_ + ct * CPG_ + c2;
#pragma unroll
  for (int pass = 0; pass < 8; pass++) {
    int n = pass * 8 + n2;
    out[(size_t)n * C_] = tile[c2][n];
  }
}

// ---------------------------------------------------------------------------
// Kernel 3: qkv GEMM, 128-n tiles. grid (32 nt, 12 ot, 4 b).
// hT tile (128n x 256c, 64 KB) staged once per block (xor-swizzled).
// ---------------------------------------------------------------------------
__global__ __launch_bounds__(256) void qkv_gemm(
    const unsigned short* __restrict__ hT, const unsigned short* __restrict__ wq,
    const float* __restrict__ qb,
    unsigned short* __restrict__ Qt, unsigned short* __restrict__ Kt,
    unsigned short* __restrict__ V) {
  int nt = blockIdx.x, ot = blockIdx.y, b = blockIdx.z;
  int t = threadIdx.x;
  int wave = t >> 6, lane = t & 63, l15 = lane & 15, quad = lane >> 4, l7 = l15 & 7;
  int o_base = ot * 64 + wave * 16;

  __shared__ __align__(16) unsigned short sh[128 * C_];
  {
    int row0 = wave * 2 + (lane >> 5);
    int col8 = lane & 31;
    int src8 = (col8 & 24) | ((col8 & 7) ^ (row0 & 7));
    const unsigned short* gsrc = hT + ((size_t)(b * N_ + nt * 128 + row0)) * C_ + src8 * 8;
#pragma unroll
    for (int it = 0; it < 16; it++)
      dma16(gsrc + (size_t)it * 8 * C_, sh + (it * 8 + wave * 2) * C_);
  }

  f32x4 acc[8];
#pragma unroll
  for (int tt = 0; tt < 8; tt++) acc[tt] = (f32x4){0.f, 0.f, 0.f, 0.f};

  const short8* arow = reinterpret_cast<const short8*>(wq + (size_t)(o_base + l15) * C_);

  asm volatile("s_waitcnt vmcnt(0)" ::: "memory");
  __syncthreads();

#pragma unroll
  for (int kk = 0; kk < 8; kk++) {
    short8 a = arow[kk * 4 + quad];
    int g = kk * 4 + quad;
    int col8 = (g & 24) | ((g & 7) ^ l7);
#pragma unroll
    for (int tt = 0; tt < 8; tt++) {
      short8 bf = *reinterpret_cast<const short8*>(&sh[(tt * 16 + l15) * C_ + col8 * 8]);
      acc[tt] = __builtin_amdgcn_mfma_f32_16x16x32_bf16(a, bf, acc[tt], 0, 0, 0);
    }
  }

  int sec = ot >> 2, head = ot & 3;
  int cw = wave * 16 + quad * 4;
  int bh = b * NH_ + head;
  const float SC = 0.125f * 1.44269504088896340736f;  // 1/sqrt(hd) * log2(e)

  if (sec == 0) {
#pragma unroll
    for (int tt = 0; tt < 8; tt++) {
      int n = nt * 128 + tt * 16 + l15;
      us4 pk;
#pragma unroll
      for (int i = 0; i < 4; i++)
        pk[i] = f2bf((acc[tt][i] + qb[ot * 64 + cw + i]) * SC);
      *reinterpret_cast<us4*>(Qt + ((size_t)bh * N_ + n) * HD_ + cw) = pk;
    }
  } else if (sec == 1) {
#pragma unroll
    for (int tt = 0; tt < 8; tt++) {
      int n = nt * 128 + tt * 16 + l15;
      us4 pk;
#pragma unroll
      for (int i = 0; i < 4; i++)
        pk[i] = f2bf(acc[tt][i] + qb[ot * 64 + cw + i]);
      *reinterpret_cast<us4*>(Kt + ((size_t)bh * N_ + n) * HD_ + cw) = pk;
    }
  } else {
#pragma unroll
    for (int tt = 0; tt < 8; tt++) {
      int n = nt * 128 + tt * 16 + l15;
#pragma unroll
      for (int i = 0; i < 4; i++)
        V[((size_t)bh * HD_ + cw + i) * N_ + n] = f2bf(acc[tt][i] + qb[ot * 64 + cw + i]);
    }
  }
}

// ---------------------------------------------------------------------------
// Kernel 4: flash attention (R4 version, best known).
// Grid 512 = (bh = blockIdx&15, qt = blockIdx>>4), 4 waves = qsub x khalf.
// Wave: 64q x 64keys/iter, 32 iters. Shared double-buffered K/V streams,
// one barrier/iter. S^T -> exp2 -> P via per-wave LDS -> PV K=32.
// ---------------------------------------------------------------------------
__global__ __launch_bounds__(256, 2) void flash_attn(
    const unsigned short* __restrict__ Qt, const unsigned short* __restrict__ Kt,
    const unsigned short* __restrict__ Vv, unsigned short* __restrict__ aoT) {
  int bh = blockIdx.x & 15, qt = blockIdx.x >> 4;
  int b = bh >> 2, head = bh & 3;
  int t = threadIdx.x;
  int wave = t >> 6, lane = t & 63, l15 = lane & 15, quad = lane >> 4;
  int l7 = l15 & 7;
  int qsub = wave >> 1, khalf = wave & 1;

  const unsigned short* Qb = Qt + (size_t)bh * N_ * HD_;
  const unsigned short* Kb = Kt + (size_t)bh * N_ * HD_;
  const unsigned short* Vb = Vv + (size_t)bh * HD_ * N_;
  int q_base = qt * 128 + qsub * 64;

  __shared__ __align__(16) unsigned char smem[74752];
  unsigned short* Ks = (unsigned short*)smem;
  unsigned short* Vs = (unsigned short*)(smem + 32768);
  unsigned short* Ps = (unsigned short*)(smem + 65536);
  float* Obuf = (float*)smem;                 // qsub*4352 + c*68 + q
  float* lbuf = (float*)(smem + 34816);       // qsub*64 + q

  const short8 vones = {(short)0x3F80, (short)0x3F80, (short)0x3F80, (short)0x3F80,
                        (short)0x3F80, (short)0x3F80, (short)0x3F80, (short)0x3F80};

  short8 qf[4][2];
#pragma unroll
  for (int r = 0; r < 4; r++)
#pragma unroll
    for (int h = 0; h < 2; h++)
      qf[r][h] = *reinterpret_cast<const short8*>(
          Qb + (size_t)(q_base + r * 16 + l15) * HD_ + h * 32 + quad * 8);

  f32x4 oa[4][4], la[4];
#pragma unroll
  for (int r = 0; r < 4; r++) {
    la[r] = (f32x4){0.f, 0.f, 0.f, 0.f};
#pragma unroll
    for (int ct = 0; ct < 4; ct++) oa[r][ct] = (f32x4){0.f, 0.f, 0.f, 0.f};
  }

  int i8 = lane >> 3, e = lane & 7;
  int perm = (e ^ i8) * 8;   // XOR swizzle of 8-element groups
  int kvoff = (khalf * 2) * 4096;
  auto stage = [&](int kt2, int buf) {
    int m0 = khalf * 2048 + kt2 * 64;
    unsigned short* Kd = Ks + kvoff + buf * 4096;
    unsigned short* Vd = Vs + kvoff + buf * 4096;
#pragma unroll
    for (int cc = 0; cc < 4; cc++) {
      int c = qsub * 4 + cc;
      dma16(Kb + (size_t)(m0 + c * 8 + i8) * HD_ + perm, Kd + c * 512);
      dma16(Vb + (size_t)(c * 8 + i8) * N_ + m0 + perm, Vd + c * 512);
    }
  };

  stage(0, 0);

  unsigned short* Pw = Ps + wave * 16 * 72;

#pragma unroll 1
  for (int kt = 0; kt < 32; kt++) {
    int buf = kt & 1;
    asm volatile("s_waitcnt vmcnt(0)" ::: "memory");
    __builtin_amdgcn_s_barrier();
    if (kt + 1 < 32) stage(kt + 1, buf ^ 1);

    const unsigned short* Kbuf = Ks + kvoff + buf * 4096;
    const unsigned short* Vbuf = Vs + kvoff + buf * 4096;

    short8 kf[4][2], vf[4][2];
#pragma unroll
    for (int tt = 0; tt < 4; tt++)
#pragma unroll
      for (int kh2 = 0; kh2 < 2; kh2++) {
        kf[tt][kh2] = *reinterpret_cast<const short8*>(
            &Kbuf[(tt * 16 + l15) * 64 + (((kh2 * 4 + quad) ^ l7) * 8)]);
        vf[tt][kh2] = *reinterpret_cast<const short8*>(
            &Vbuf[(tt * 16 + l15) * 64 + (((kh2 * 4 + quad) ^ l7) * 8)]);
      }

#pragma unroll
    for (int r = 0; r < 4; r++) {
      f32x4 s[4];
#pragma unroll
      for (int tt = 0; tt < 4; tt++) {
        f32x4 z = (f32x4){0.f, 0.f, 0.f, 0.f};
        z = __builtin_amdgcn_mfma_f32_16x16x32_bf16(kf[tt][0], qf[r][0], z, 0, 0, 0);
        s[tt] = __builtin_amdgcn_mfma_f32_16x16x32_bf16(kf[tt][1], qf[r][1], z, 0, 0, 0);
      }
#pragma unroll
      for (int tt = 0; tt < 4; tt++) {
        union { unsigned u2[2]; us4 v; } w;
        w.u2[0] = pkbf2(__builtin_amdgcn_exp2f(s[tt][0]), __builtin_amdgcn_exp2f(s[tt][1]));
        w.u2[1] = pkbf2(__builtin_amdgcn_exp2f(s[tt][2]), __builtin_amdgcn_exp2f(s[tt][3]));
        *reinterpret_cast<us4*>(&Pw[l15 * 72 + tt * 16 + quad * 4]) = w.v;
      }
      short8 pf0 = *reinterpret_cast<const short8*>(&Pw[l15 * 72 + quad * 8]);
      short8 pf1 = *reinterpret_cast<const short8*>(&Pw[l15 * 72 + 32 + quad * 8]);
#pragma unroll
      for (int ct = 0; ct < 4; ct++) {
        oa[r][ct] = __builtin_amdgcn_mfma_f32_16x16x32_bf16(vf[ct][0], pf0, oa[r][ct], 0, 0, 0);
        oa[r][ct] = __builtin_amdgcn_mfma_f32_16x16x32_bf16(vf[ct][1], pf1, oa[r][ct], 0, 0, 0);
      }
      la[r] = __builtin_amdgcn_mfma_f32_16x16x32_bf16(vones, pf0, la[r], 0, 0, 0);
      la[r] = __builtin_amdgcn_mfma_f32_16x16x32_bf16(vones, pf1, la[r], 0, 0, 0);
    }
  }

  // ---- merge the two key-halves (exact: plain add, no max-sub) ----
  __builtin_amdgcn_s_barrier();
  if (khalf == 1) {
#pragma unroll
    for (int r = 0; r < 4; r++) {
#pragma unroll
      for (int ct = 0; ct < 4; ct++)
#pragma unroll
        for (int i = 0; i < 4; i++)
          Obuf[qsub * 4352 + (ct * 16 + quad * 4 + i) * 68 + r * 16 + l15] = oa[r][ct][i];
      if (quad == 0) lbuf[qsub * 64 + r * 16 + l15] = la[r][0];
    }
  }
  __builtin_amdgcn_s_barrier();
  if (khalf == 0) {
#pragma unroll
    for (int r = 0; r < 4; r++) {
      float inv = 1.0f / (la[r][0] + lbuf[qsub * 64 + r * 16 + l15]);
      int n = q_base + r * 16 + l15;
#pragma unroll
      for (int ct = 0; ct < 4; ct++) {
        const float* ob = &Obuf[qsub * 4352 + (ct * 16 + quad * 4) * 68 + r * 16 + l15];
        union { unsigned u2[2]; us4 v; } w;
        w.u2[0] = pkbf2((oa[r][ct][0] + ob[0]) * inv, (oa[r][ct][1] + ob[68]) * inv);
        w.u2[1] = pkbf2((oa[r][ct][2] + ob[136]) * inv, (oa[r][ct][3] + ob[204]) * inv);
        *reinterpret_cast<us4*>(
            aoT + ((size_t)(b * N_ + n)) * C_ + head * HD_ + ct * 16 + quad * 4) = w.v;
      }
    }
  }
}

// ---------------------------------------------------------------------------
// Kernel 5: proj GEMM + bias + residual, 128-n tiles. grid (32 nt, 4 ot, 4 b).
// ---------------------------------------------------------------------------
__global__ __launch_bounds__(256) void proj_gemm(
    const unsigned short* __restrict__ aoT, const unsigned short* __restrict__ wp,
    const float* __restrict__ pb, const float* __restrict__ x,
    float* __restrict__ out) {
  int nt = blockIdx.x, ot = blockIdx.y, b = blockIdx.z;
  int t = threadIdx.x;
  int wave = t >> 6, lane = t & 63, l15 = lane & 15, quad = lane >> 4, l7 = l15 & 7;
  int o_base = ot * 64 + wave * 16;

  __shared__ __align__(16) unsigned short sh[128 * C_];
  {
    int row0 = wave * 2 + (lane >> 5);
    int col8 = lane & 31;
    int src8 = (col8 & 24) | ((col8 & 7) ^ (row0 & 7));
    const unsigned short* gsrc = aoT + ((size_t)(b * N_ + nt * 128 + row0)) * C_ + src8 * 8;
#pragma unroll
    for (int it = 0; it < 16; it++)
      dma16(gsrc + (size_t)it * 8 * C_, sh + (it * 8 + wave * 2) * C_);
  }

  f32x4 acc[8];
#pragma unroll
  for (int tt = 0; tt < 8; tt++) acc[tt] = (f32x4){0.f, 0.f, 0.f, 0.f};

  const short8* arow = reinterpret_cast<const short8*>(wp + (size_t)(o_base + l15) * C_);

  asm volatile("s_waitcnt vmcnt(0)" ::: "memory");
  __syncthreads();

#pragma unroll
  for (int kk = 0; kk < 8; kk++) {
    short8 a = arow[kk * 4 + quad];
    int g = kk * 4 + quad;
    int col8 = (g & 24) | ((g & 7) ^ l7);
#pragma unroll
    for (int tt = 0; tt < 8; tt++) {
      short8 bf = *reinterpret_cast<const short8*>(&sh[(tt * 16 + l15) * C_ + col8 * 8]);
      acc[tt] = __builtin_amdgcn_mfma_f32_16x16x32_bf16(a, bf, acc[tt], 0, 0, 0);
    }
  }
#pragma unroll
  for (int tt = 0; tt < 8; tt++) {
    int n = nt * 128 + tt * 16 + l15;
#pragma unroll
    for (int i = 0; i < 4; i++) {
      int o = o_base + quad * 4 + i;
      size_t idx = ((size_t)(b * C_ + o)) * N_ + n;
      out[idx] = acc[tt][i] + pb[o] + x[idx];
    }
  }
}

// ---------------------------------------------------------------------------
extern "C" void kernel_launch(void* const* d_in, const int* in_sizes, int n_in,
                              void* d_out, int out_size, void* d_ws, size_t ws_size,
                              hipStream_t stream) {
  const float* x      = (const float*)d_in[0];
  const float* norm_w = (const float*)d_in[1];
  const float* norm_b = (const float*)d_in[2];
  const float* qkv_w  = (const float*)d_in[3];
  const float* qkv_b  = (const float*)d_in[4];
  const float* proj_w = (const float*)d_in[5];
  const float* proj_b = (const float*)d_in[6];
  float* out = (float*)d_out;

  char* ws = (char*)d_ws;
  size_t off = 0;
  auto alloc = [&](size_t bytes) { size_t o = off; off = (off + bytes + 255) & ~(size_t)255; return o; };
  size_t off_partial = alloc(512 * 2 * sizeof(float));
  size_t off_stats   = alloc(32 * 2 * sizeof(float));   // unused (kept for layout stability)
  size_t off_wq      = alloc((size_t)768 * 256 * 2);
  size_t off_wp      = alloc((size_t)256 * 256 * 2);
  size_t off_hT      = alloc((size_t)B_ * N_ * C_ * 2);
  size_t off_Qt      = alloc((size_t)B_ * NH_ * N_ * HD_ * 2);
  size_t off_Kt      = alloc((size_t)B_ * NH_ * N_ * HD_ * 2);
  size_t off_V       = alloc((size_t)B_ * NH_ * HD_ * N_ * 2);
  size_t off_aoT     = alloc((size_t)B_ * N_ * C_ * 2);
  (void)off_stats;

  float* partial = (float*)(ws + off_partial);
  unsigned short* wq  = (unsigned short*)(ws + off_wq);
  unsigned short* wp  = (unsigned short*)(ws + off_wp);
  unsigned short* hT  = (unsigned short*)(ws + off_hT);
  unsigned short* Qt  = (unsigned short*)(ws + off_Qt);
  unsigned short* Kt  = (unsigned short*)(ws + off_Kt);
  unsigned short* V   = (unsigned short*)(ws + off_V);
  unsigned short* aoT = (unsigned short*)(ws + off_aoT);

  gn_partial_cvt<<<1280, 256, 0, stream>>>(x, partial, qkv_w, proj_w, wq, wp);
  gn_apply<<<dim3(64, 8, 4), 256, 0, stream>>>(x, norm_w, norm_b, partial, hT);
  qkv_gemm<<<dim3(32, 12, 4), 256, 0, stream>>>(hT, wq, qkv_b, Qt, Kt, V);
  flash_attn<<<512, 256, 0, stream>>>(Qt, Kt, V, aoT);
  proj_gemm<<<dim3(32, 4, 4), 256, 0, stream>>>(aoT, wp, proj_b, x, out);
}

// Round 11
// 193.305 us; speedup vs baseline: 1.1541x; 1.0015x over previous
//
#include <hip/hip_runtime.h>
#include <hip/hip_bf16.h>
#include <stdint.h>

// ---------------------------------------------------------------------------
// SelfAttention2d: B=4, C=256, H=W=64 (N=4096), NUM_HEADS=4 (hd=64), GROUPS=8
// R10: R9 + XCD-aware 1D grids for qkv/proj (all ot-blocks sharing one
//      staged tile land on the same XCD: idx = ot*128 + nt*4 + b, so fixed
//      (nt,b) => idx mod 8 constant => same-XCD L2 hits for re-staging).
//      Flash: prefetch issued before the vmcnt wait (vmcnt(8) waits only the
//      current tile's 8 DMAs). Everything else identical to R9 (193.6 us).
// ---------------------------------------------------------------------------

#define B_  4
#define C_  256
#define N_  4096
#define NH_ 4
#define HD_ 64
#define G_  8
#define CPG_ 32
#define GRP_ELEMS (CPG_ * N_)

typedef __attribute__((ext_vector_type(8))) short short8;
typedef __attribute__((ext_vector_type(4))) float f32x4;
typedef __attribute__((ext_vector_type(4))) unsigned short us4;

__device__ __forceinline__ unsigned short f2bf(float f) {
  union { float f; unsigned u; } v; v.f = f;
  unsigned r = v.u + 0x7FFFu + ((v.u >> 16) & 1u);
  return (unsigned short)(r >> 16);
}

// packed fp32x2 -> bf16x2 (v_cvt_pk_bf16_f32 on gfx950)
__device__ __forceinline__ unsigned pkbf2(float a, float b) {
  __hip_bfloat162 h = __float22bfloat162_rn(make_float2(a, b));
  unsigned r; __builtin_memcpy(&r, &h, sizeof(r)); return r;
}

// async 16B/lane global->LDS DMA; LDS dest = uniform base + lane*16
__device__ __forceinline__ void dma16(const unsigned short* g, unsigned short* l) {
  __builtin_amdgcn_global_load_lds(
      (const __attribute__((address_space(1))) unsigned int*)(g),
      (__attribute__((address_space(3))) unsigned int*)(l), 16, 0, 0);
}

// ---------------------------------------------------------------------------
// Kernel 1: gn_partial (blocks 0..511) + weight conversion (blocks 512..1279).
// ---------------------------------------------------------------------------
__global__ void gn_partial_cvt(const float* __restrict__ x, float* __restrict__ partial,
                               const float* __restrict__ qkvw, const float* __restrict__ projw,
                               unsigned short* __restrict__ wq, unsigned short* __restrict__ wp) {
  __shared__ float ls[8];
  int t = threadIdx.x;
  if (blockIdx.x >= 512) {
    int i = (blockIdx.x - 512) * 256 + t;
    if (i < 768 * 256) wq[i] = f2bf(qkvw[i]);
    if (i < 256 * 256) wp[i] = f2bf(projw[i]);
    return;
  }
  int idx = blockIdx.x;
  int slice = idx & 15, g = (idx >> 4) & 7, b = idx >> 7;
  const float* base = x + (size_t)(b * C_ + g * CPG_) * N_ + slice * 256;
  float s = 0.f, sq = 0.f;
#pragma unroll
  for (int cc = 0; cc < CPG_; cc++) {
    float v = base[(size_t)cc * N_ + t];
    s += v; sq += v * v;
  }
#pragma unroll
  for (int off = 32; off; off >>= 1) {
    s  += __shfl_down(s,  off, 64);
    sq += __shfl_down(sq, off, 64);
  }
  int wave = t >> 6, lane = t & 63;
  if (lane == 0) { ls[wave * 2] = s; ls[wave * 2 + 1] = sq; }
  __syncthreads();
  if (t == 0) {
    float S = ls[0] + ls[2] + ls[4] + ls[6];
    float SQ = ls[1] + ls[3] + ls[5] + ls[7];
    partial[idx * 2] = S; partial[idx * 2 + 1] = SQ;
  }
}

// ---------------------------------------------------------------------------
// Kernel 2: normalize + transpose with INLINE stats. x -> hT (B,N,C) bf16.
// ---------------------------------------------------------------------------
__global__ void gn_apply(const float* __restrict__ x,
                         const float* __restrict__ nw, const float* __restrict__ nb,
                         const float* __restrict__ partial, unsigned short* __restrict__ hT) {
  int nt = blockIdx.x, ct = blockIdx.y, b = blockIdx.z;
  __shared__ unsigned short tile[32][72];
  int t = threadIdx.x;
  int lane = t & 63;
  int grp = b * G_ + ct;
  float s = 0.f, sq = 0.f;
  if (lane < 16) {
    s  = partial[(grp * 16 + lane) * 2];
    sq = partial[(grp * 16 + lane) * 2 + 1];
  }
#pragma unroll
  for (int off = 8; off; off >>= 1) {
    s  += __shfl_down(s,  off, 64);
    sq += __shfl_down(sq, off, 64);
  }
  s  = __shfl(s,  0, 64);
  sq = __shfl(sq, 0, 64);
  const float inv = 1.0f / (float)GRP_ELEMS;
  float mean = s * inv;
  float rstd = rsqrtf(sq * inv - mean * mean + 1e-5f);

  int n_loc = t & 63, c_loc = t >> 6;
  const float* xb = x + (size_t)(b * C_ + ct * CPG_) * N_ + nt * 64;
#pragma unroll
  for (int rr = 0; rr < 8; rr++) {
    int cc = rr * 4 + c_loc;
    int c = ct * CPG_ + cc;
    float v = xb[(size_t)cc * N_ + n_loc];
    v = (v - mean) * rstd * nw[c] + nb[c];
    tile[cc][n_loc] = f2bf(v);
  }
  __syncthreads();
  int c2 = t & 31, n2 = t >> 5;
  unsigned short* out = hT + ((size_t)(b * N_ + nt * 64)) * C_ + ct * CPG_ + c2;
#pragma unroll
  for (int pass = 0; pass < 8; pass++) {
    int n = pass * 8 + n2;
    out[(size_t)n * C_] = tile[c2][n];
  }
}

// ---------------------------------------------------------------------------
// Kernel 3: qkv GEMM, 128-n tiles, 1D XCD-aware grid (1536 blocks):
// idx = ot*128 + nt*4 + b  =>  fixed (nt,b) tile => same XCD for all 12 ot.
// ---------------------------------------------------------------------------
__global__ __launch_bounds__(256) void qkv_gemm(
    const unsigned short* __restrict__ hT, const unsigned short* __restrict__ wq,
    const float* __restrict__ qb,
    unsigned short* __restrict__ Qt, unsigned short* __restrict__ Kt,
    unsigned short* __restrict__ V) {
  int ot = blockIdx.x >> 7;
  int nt = (blockIdx.x & 127) >> 2;
  int b  = blockIdx.x & 3;
  int t = threadIdx.x;
  int wave = t >> 6, lane = t & 63, l15 = lane & 15, quad = lane >> 4, l7 = l15 & 7;
  int o_base = ot * 64 + wave * 16;

  __shared__ __align__(16) unsigned short sh[128 * C_];
  {
    int row0 = wave * 2 + (lane >> 5);
    int col8 = lane & 31;
    int src8 = (col8 & 24) | ((col8 & 7) ^ (row0 & 7));
    const unsigned short* gsrc = hT + ((size_t)(b * N_ + nt * 128 + row0)) * C_ + src8 * 8;
#pragma unroll
    for (int it = 0; it < 16; it++)
      dma16(gsrc + (size_t)it * 8 * C_, sh + (it * 8 + wave * 2) * C_);
  }

  f32x4 acc[8];
#pragma unroll
  for (int tt = 0; tt < 8; tt++) acc[tt] = (f32x4){0.f, 0.f, 0.f, 0.f};

  const short8* arow = reinterpret_cast<const short8*>(wq + (size_t)(o_base + l15) * C_);

  asm volatile("s_waitcnt vmcnt(0)" ::: "memory");
  __syncthreads();

#pragma unroll
  for (int kk = 0; kk < 8; kk++) {
    short8 a = arow[kk * 4 + quad];
    int g = kk * 4 + quad;
    int col8 = (g & 24) | ((g & 7) ^ l7);
#pragma unroll
    for (int tt = 0; tt < 8; tt++) {
      short8 bf = *reinterpret_cast<const short8*>(&sh[(tt * 16 + l15) * C_ + col8 * 8]);
      acc[tt] = __builtin_amdgcn_mfma_f32_16x16x32_bf16(a, bf, acc[tt], 0, 0, 0);
    }
  }

  int sec = ot >> 2, head = ot & 3;
  int cw = wave * 16 + quad * 4;
  int bh = b * NH_ + head;
  const float SC = 0.125f * 1.44269504088896340736f;  // 1/sqrt(hd) * log2(e)

  if (sec == 0) {
#pragma unroll
    for (int tt = 0; tt < 8; tt++) {
      int n = nt * 128 + tt * 16 + l15;
      us4 pk;
#pragma unroll
      for (int i = 0; i < 4; i++)
        pk[i] = f2bf((acc[tt][i] + qb[ot * 64 + cw + i]) * SC);
      *reinterpret_cast<us4*>(Qt + ((size_t)bh * N_ + n) * HD_ + cw) = pk;
    }
  } else if (sec == 1) {
#pragma unroll
    for (int tt = 0; tt < 8; tt++) {
      int n = nt * 128 + tt * 16 + l15;
      us4 pk;
#pragma unroll
      for (int i = 0; i < 4; i++)
        pk[i] = f2bf(acc[tt][i] + qb[ot * 64 + cw + i]);
      *reinterpret_cast<us4*>(Kt + ((size_t)bh * N_ + n) * HD_ + cw) = pk;
    }
  } else {
#pragma unroll
    for (int tt = 0; tt < 8; tt++) {
      int n = nt * 128 + tt * 16 + l15;
#pragma unroll
      for (int i = 0; i < 4; i++)
        V[((size_t)bh * HD_ + cw + i) * N_ + n] = f2bf(acc[tt][i] + qb[ot * 64 + cw + i]);
    }
  }
}

// ---------------------------------------------------------------------------
// Kernel 4: flash attention (R4 structure). Prefetch issued before the wait:
// vmcnt(8) waits only the oldest 8 (tile kt's DMAs); last iter uses vmcnt(0).
// ---------------------------------------------------------------------------
__global__ __launch_bounds__(256, 2) void flash_attn(
    const unsigned short* __restrict__ Qt, const unsigned short* __restrict__ Kt,
    const unsigned short* __restrict__ Vv, unsigned short* __restrict__ aoT) {
  int bh = blockIdx.x & 15, qt = blockIdx.x >> 4;
  int b = bh >> 2, head = bh & 3;
  int t = threadIdx.x;
  int wave = t >> 6, lane = t & 63, l15 = lane & 15, quad = lane >> 4;
  int l7 = l15 & 7;
  int qsub = wave >> 1, khalf = wave & 1;

  const unsigned short* Qb = Qt + (size_t)bh * N_ * HD_;
  const unsigned short* Kb = Kt + (size_t)bh * N_ * HD_;
  const unsigned short* Vb = Vv + (size_t)bh * HD_ * N_;
  int q_base = qt * 128 + qsub * 64;

  __shared__ __align__(16) unsigned char smem[74752];
  unsigned short* Ks = (unsigned short*)smem;
  unsigned short* Vs = (unsigned short*)(smem + 32768);
  unsigned short* Ps = (unsigned short*)(smem + 65536);
  float* Obuf = (float*)smem;                 // qsub*4352 + c*68 + q
  float* lbuf = (float*)(smem + 34816);       // qsub*64 + q

  const short8 vones = {(short)0x3F80, (short)0x3F80, (short)0x3F80, (short)0x3F80,
                        (short)0x3F80, (short)0x3F80, (short)0x3F80, (short)0x3F80};

  short8 qf[4][2];
#pragma unroll
  for (int r = 0; r < 4; r++)
#pragma unroll
    for (int h = 0; h < 2; h++)
      qf[r][h] = *reinterpret_cast<const short8*>(
          Qb + (size_t)(q_base + r * 16 + l15) * HD_ + h * 32 + quad * 8);

  f32x4 oa[4][4], la[4];
#pragma unroll
  for (int r = 0; r < 4; r++) {
    la[r] = (f32x4){0.f, 0.f, 0.f, 0.f};
#pragma unroll
    for (int ct = 0; ct < 4; ct++) oa[r][ct] = (f32x4){0.f, 0.f, 0.f, 0.f};
  }

  int i8 = lane >> 3, e = lane & 7;
  int perm = (e ^ i8) * 8;   // XOR swizzle of 8-element groups
  int kvoff = (khalf * 2) * 4096;
  auto stage = [&](int kt2, int buf) {
    int m0 = khalf * 2048 + kt2 * 64;
    unsigned short* Kd = Ks + kvoff + buf * 4096;
    unsigned short* Vd = Vs + kvoff + buf * 4096;
#pragma unroll
    for (int cc = 0; cc < 4; cc++) {
      int c = qsub * 4 + cc;
      dma16(Kb + (size_t)(m0 + c * 8 + i8) * HD_ + perm, Kd + c * 512);
      dma16(Vb + (size_t)(c * 8 + i8) * N_ + m0 + perm, Vd + c * 512);
    }
  };

  stage(0, 0);

  unsigned short* Pw = Ps + wave * 16 * 72;

#pragma unroll 1
  for (int kt = 0; kt < 32; kt++) {
    int buf = kt & 1;
    if (kt + 1 < 32) {
      stage(kt + 1, buf ^ 1);                          // issue prefetch first
      asm volatile("s_waitcnt vmcnt(8)" ::: "memory"); // wait only tile kt's 8
    } else {
      asm volatile("s_waitcnt vmcnt(0)" ::: "memory");
    }
    __builtin_amdgcn_s_barrier();

    const unsigned short* Kbuf = Ks + kvoff + buf * 4096;
    const unsigned short* Vbuf = Vs + kvoff + buf * 4096;

    short8 kf[4][2], vf[4][2];
#pragma unroll
    for (int tt = 0; tt < 4; tt++)
#pragma unroll
      for (int kh2 = 0; kh2 < 2; kh2++) {
        kf[tt][kh2] = *reinterpret_cast<const short8*>(
            &Kbuf[(tt * 16 + l15) * 64 + (((kh2 * 4 + quad) ^ l7) * 8)]);
        vf[tt][kh2] = *reinterpret_cast<const short8*>(
            &Vbuf[(tt * 16 + l15) * 64 + (((kh2 * 4 + quad) ^ l7) * 8)]);
      }

#pragma unroll
    for (int r = 0; r < 4; r++) {
      f32x4 s[4];
#pragma unroll
      for (int tt = 0; tt < 4; tt++) {
        f32x4 z = (f32x4){0.f, 0.f, 0.f, 0.f};
        z = __builtin_amdgcn_mfma_f32_16x16x32_bf16(kf[tt][0], qf[r][0], z, 0, 0, 0);
        s[tt] = __builtin_amdgcn_mfma_f32_16x16x32_bf16(kf[tt][1], qf[r][1], z, 0, 0, 0);
      }
#pragma unroll
      for (int tt = 0; tt < 4; tt++) {
        union { unsigned u2[2]; us4 v; } w;
        w.u2[0] = pkbf2(__builtin_amdgcn_exp2f(s[tt][0]), __builtin_amdgcn_exp2f(s[tt][1]));
        w.u2[1] = pkbf2(__builtin_amdgcn_exp2f(s[tt][2]), __builtin_amdgcn_exp2f(s[tt][3]));
        *reinterpret_cast<us4*>(&Pw[l15 * 72 + tt * 16 + quad * 4]) = w.v;
      }
      short8 pf0 = *reinterpret_cast<const short8*>(&Pw[l15 * 72 + quad * 8]);
      short8 pf1 = *reinterpret_cast<const short8*>(&Pw[l15 * 72 + 32 + quad * 8]);
#pragma unroll
      for (int ct = 0; ct < 4; ct++) {
        oa[r][ct] = __builtin_amdgcn_mfma_f32_16x16x32_bf16(vf[ct][0], pf0, oa[r][ct], 0, 0, 0);
        oa[r][ct] = __builtin_amdgcn_mfma_f32_16x16x32_bf16(vf[ct][1], pf1, oa[r][ct], 0, 0, 0);
      }
      la[r] = __builtin_amdgcn_mfma_f32_16x16x32_bf16(vones, pf0, la[r], 0, 0, 0);
      la[r] = __builtin_amdgcn_mfma_f32_16x16x32_bf16(vones, pf1, la[r], 0, 0, 0);
    }
  }

  // ---- merge the two key-halves (exact: plain add, no max-sub) ----
  __builtin_amdgcn_s_barrier();
  if (khalf == 1) {
#pragma unroll
    for (int r = 0; r < 4; r++) {
#pragma unroll
      for (int ct = 0; ct < 4; ct++)
#pragma unroll
        for (int i = 0; i < 4; i++)
          Obuf[qsub * 4352 + (ct * 16 + quad * 4 + i) * 68 + r * 16 + l15] = oa[r][ct][i];
      if (quad == 0) lbuf[qsub * 64 + r * 16 + l15] = la[r][0];
    }
  }
  __builtin_amdgcn_s_barrier();
  if (khalf == 0) {
#pragma unroll
    for (int r = 0; r < 4; r++) {
      float inv = 1.0f / (la[r][0] + lbuf[qsub * 64 + r * 16 + l15]);
      int n = q_base + r * 16 + l15;
#pragma unroll
      for (int ct = 0; ct < 4; ct++) {
        const float* ob = &Obuf[qsub * 4352 + (ct * 16 + quad * 4) * 68 + r * 16 + l15];
        union { unsigned u2[2]; us4 v; } w;
        w.u2[0] = pkbf2((oa[r][ct][0] + ob[0]) * inv, (oa[r][ct][1] + ob[68]) * inv);
        w.u2[1] = pkbf2((oa[r][ct][2] + ob[136]) * inv, (oa[r][ct][3] + ob[204]) * inv);
        *reinterpret_cast<us4*>(
            aoT + ((size_t)(b * N_ + n)) * C_ + head * HD_ + ct * 16 + quad * 4) = w.v;
      }
    }
  }
}

// ---------------------------------------------------------------------------
// Kernel 5: proj GEMM + bias + residual, 128-n tiles, 1D XCD-aware grid
// (512 blocks): idx = ot*128 + nt*4 + b.
// ---------------------------------------------------------------------------
__global__ __launch_bounds__(256) void proj_gemm(
    const unsigned short* __restrict__ aoT, const unsigned short* __restrict__ wp,
    const float* __restrict__ pb, const float* __restrict__ x,
    float* __restrict__ out) {
  int ot = blockIdx.x >> 7;
  int nt = (blockIdx.x & 127) >> 2;
  int b  = blockIdx.x & 3;
  int t = threadIdx.x;
  int wave = t >> 6, lane = t & 63, l15 = lane & 15, quad = lane >> 4, l7 = l15 & 7;
  int o_base = ot * 64 + wave * 16;

  __shared__ __align__(16) unsigned short sh[128 * C_];
  {
    int row0 = wave * 2 + (lane >> 5);
    int col8 = lane & 31;
    int src8 = (col8 & 24) | ((col8 & 7) ^ (row0 & 7));
    const unsigned short* gsrc = aoT + ((size_t)(b * N_ + nt * 128 + row0)) * C_ + src8 * 8;
#pragma unroll
    for (int it = 0; it < 16; it++)
      dma16(gsrc + (size_t)it * 8 * C_, sh + (it * 8 + wave * 2) * C_);
  }

  f32x4 acc[8];
#pragma unroll
  for (int tt = 0; tt < 8; tt++) acc[tt] = (f32x4){0.f, 0.f, 0.f, 0.f};

  const short8* arow = reinterpret_cast<const short8*>(wp + (size_t)(o_base + l15) * C_);

  asm volatile("s_waitcnt vmcnt(0)" ::: "memory");
  __syncthreads();

#pragma unroll
  for (int kk = 0; kk < 8; kk++) {
    short8 a = arow[kk * 4 + quad];
    int g = kk * 4 + quad;
    int col8 = (g & 24) | ((g & 7) ^ l7);
#pragma unroll
    for (int tt = 0; tt < 8; tt++) {
      short8 bf = *reinterpret_cast<const short8*>(&sh[(tt * 16 + l15) * C_ + col8 * 8]);
      acc[tt] = __builtin_amdgcn_mfma_f32_16x16x32_bf16(a, bf, acc[tt], 0, 0, 0);
    }
  }
#pragma unroll
  for (int tt = 0; tt < 8; tt++) {
    int n = nt * 128 + tt * 16 + l15;
#pragma unroll
    for (int i = 0; i < 4; i++) {
      int o = o_base + quad * 4 + i;
      size_t idx = ((size_t)(b * C_ + o)) * N_ + n;
      out[idx] = acc[tt][i] + pb[o] + x[idx];
    }
  }
}

// ---------------------------------------------------------------------------
extern "C" void kernel_launch(void* const* d_in, const int* in_sizes, int n_in,
                              void* d_out, int out_size, void* d_ws, size_t ws_size,
                              hipStream_t stream) {
  const float* x      = (const float*)d_in[0];
  const float* norm_w = (const float*)d_in[1];
  const float* norm_b = (const float*)d_in[2];
  const float* qkv_w  = (const float*)d_in[3];
  const float* qkv_b  = (const float*)d_in[4];
  const float* proj_w = (const float*)d_in[5];
  const float* proj_b = (const float*)d_in[6];
  float* out = (float*)d_out;

  char* ws = (char*)d_ws;
  size_t off = 0;
  auto alloc = [&](size_t bytes) { size_t o = off; off = (off + bytes + 255) & ~(size_t)255; return o; };
  size_t off_partial = alloc(512 * 2 * sizeof(float));
  size_t off_stats   = alloc(32 * 2 * sizeof(float));   // unused (layout stability)
  size_t off_wq      = alloc((size_t)768 * 256 * 2);
  size_t off_wp      = alloc((size_t)256 * 256 * 2);
  size_t off_hT      = alloc((size_t)B_ * N_ * C_ * 2);
  size_t off_Qt      = alloc((size_t)B_ * NH_ * N_ * HD_ * 2);
  size_t off_Kt      = alloc((size_t)B_ * NH_ * N_ * HD_ * 2);
  size_t off_V       = alloc((size_t)B_ * NH_ * HD_ * N_ * 2);
  size_t off_aoT     = alloc((size_t)B_ * N_ * C_ * 2);
  (void)off_stats;

  float* partial = (float*)(ws + off_partial);
  unsigned short* wq  = (unsigned short*)(ws + off_wq);
  unsigned short* wp  = (unsigned short*)(ws + off_wp);
  unsigned short* hT  = (unsigned short*)(ws + off_hT);
  unsigned short* Qt  = (unsigned short*)(ws + off_Qt);
  unsigned short* Kt  = (unsigned short*)(ws + off_Kt);
  unsigned short* V   = (unsigned short*)(ws + off_V);
  unsigned short* aoT = (unsigned short*)(ws + off_aoT);

  gn_partial_cvt<<<1280, 256, 0, stream>>>(x, partial, qkv_w, proj_w, wq, wp);
  gn_apply<<<dim3(64, 8, 4), 256, 0, stream>>>(x, norm_w, norm_b, partial, hT);
  qkv_gemm<<<1536, 256, 0, stream>>>(hT, wq, qkv_b, Qt, Kt, V);
  flash_attn<<<512, 256, 0, stream>>>(Qt, Kt, V, aoT);
  proj_gemm<<<512, 256, 0, stream>>>(aoT, wp, proj_b, x, out);
}

// Round 12
// 192.523 us; speedup vs baseline: 1.1588x; 1.0041x over previous
//
#include <hip/hip_runtime.h>
#include <hip/hip_bf16.h>
#include <stdint.h>

// ---------------------------------------------------------------------------
// SelfAttention2d: B=4, C=256, H=W=64 (N=4096), NUM_HEADS=4 (hd=64), GROUPS=8
// R11: qkv widened to 128-o blocks (staging redundancy 12->6, 2 MFMAs per
//      B-frag ds_read), grid 768 XCD-affine. gn_apply: packed b128 stores.
//      flash/proj/gn_partial = R10 (flash at its ~777 TF HIP-source plateau).
// ---------------------------------------------------------------------------

#define B_  4
#define C_  256
#define N_  4096
#define NH_ 4
#define HD_ 64
#define G_  8
#define CPG_ 32
#define GRP_ELEMS (CPG_ * N_)

typedef __attribute__((ext_vector_type(8))) short short8;
typedef __attribute__((ext_vector_type(4))) float f32x4;
typedef __attribute__((ext_vector_type(4))) unsigned short us4;

__device__ __forceinline__ unsigned short f2bf(float f) {
  union { float f; unsigned u; } v; v.f = f;
  unsigned r = v.u + 0x7FFFu + ((v.u >> 16) & 1u);
  return (unsigned short)(r >> 16);
}

// packed fp32x2 -> bf16x2 (v_cvt_pk_bf16_f32 on gfx950)
__device__ __forceinline__ unsigned pkbf2(float a, float b) {
  __hip_bfloat162 h = __float22bfloat162_rn(make_float2(a, b));
  unsigned r; __builtin_memcpy(&r, &h, sizeof(r)); return r;
}

// async 16B/lane global->LDS DMA; LDS dest = uniform base + lane*16
__device__ __forceinline__ void dma16(const unsigned short* g, unsigned short* l) {
  __builtin_amdgcn_global_load_lds(
      (const __attribute__((address_space(1))) unsigned int*)(g),
      (__attribute__((address_space(3))) unsigned int*)(l), 16, 0, 0);
}

// ---------------------------------------------------------------------------
// Kernel 1: gn_partial (blocks 0..511) + weight conversion (blocks 512..1279).
// ---------------------------------------------------------------------------
__global__ void gn_partial_cvt(const float* __restrict__ x, float* __restrict__ partial,
                               const float* __restrict__ qkvw, const float* __restrict__ projw,
                               unsigned short* __restrict__ wq, unsigned short* __restrict__ wp) {
  __shared__ float ls[8];
  int t = threadIdx.x;
  if (blockIdx.x >= 512) {
    int i = (blockIdx.x - 512) * 256 + t;
    if (i < 768 * 256) wq[i] = f2bf(qkvw[i]);
    if (i < 256 * 256) wp[i] = f2bf(projw[i]);
    return;
  }
  int idx = blockIdx.x;
  int slice = idx & 15, g = (idx >> 4) & 7, b = idx >> 7;
  const float* base = x + (size_t)(b * C_ + g * CPG_) * N_ + slice * 256;
  float s = 0.f, sq = 0.f;
#pragma unroll
  for (int cc = 0; cc < CPG_; cc++) {
    float v = base[(size_t)cc * N_ + t];
    s += v; sq += v * v;
  }
#pragma unroll
  for (int off = 32; off; off >>= 1) {
    s  += __shfl_down(s,  off, 64);
    sq += __shfl_down(sq, off, 64);
  }
  int wave = t >> 6, lane = t & 63;
  if (lane == 0) { ls[wave * 2] = s; ls[wave * 2 + 1] = sq; }
  __syncthreads();
  if (t == 0) {
    float S = ls[0] + ls[2] + ls[4] + ls[6];
    float SQ = ls[1] + ls[3] + ls[5] + ls[7];
    partial[idx * 2] = S; partial[idx * 2 + 1] = SQ;
  }
}

// ---------------------------------------------------------------------------
// Kernel 2: normalize + transpose with INLINE stats. x -> hT (B,N,C) bf16.
// Epilogue: one b128 store per thread (c8 = (t&3)*8 within group, n = t>>2).
// ---------------------------------------------------------------------------
__global__ void gn_apply(const float* __restrict__ x,
                         const float* __restrict__ nw, const float* __restrict__ nb,
                         const float* __restrict__ partial, unsigned short* __restrict__ hT) {
  int nt = blockIdx.x, ct = blockIdx.y, b = blockIdx.z;
  __shared__ unsigned short tile[32][72];
  int t = threadIdx.x;
  int lane = t & 63;
  int grp = b * G_ + ct;
  float s = 0.f, sq = 0.f;
  if (lane < 16) {
    s  = partial[(grp * 16 + lane) * 2];
    sq = partial[(grp * 16 + lane) * 2 + 1];
  }
#pragma unroll
  for (int off = 8; off; off >>= 1) {
    s  += __shfl_down(s,  off, 64);
    sq += __shfl_down(sq, off, 64);
  }
  s  = __shfl(s,  0, 64);
  sq = __shfl(sq, 0, 64);
  const float inv = 1.0f / (float)GRP_ELEMS;
  float mean = s * inv;
  float rstd = rsqrtf(sq * inv - mean * mean + 1e-5f);

  int n_loc = t & 63, c_loc = t >> 6;
  const float* xb = x + (size_t)(b * C_ + ct * CPG_) * N_ + nt * 64;
#pragma unroll
  for (int rr = 0; rr < 8; rr++) {
    int cc = rr * 4 + c_loc;
    int c = ct * CPG_ + cc;
    float v = xb[(size_t)cc * N_ + n_loc];
    v = (v - mean) * rstd * nw[c] + nb[c];
    tile[cc][n_loc] = f2bf(v);
  }
  __syncthreads();
  // packed write: thread handles n = t>>2, 8 consecutive c = (t&3)*8
  int n = t >> 2, c8 = (t & 3) * 8;
  us4 lo, hi;
#pragma unroll
  for (int j = 0; j < 4; j++) lo[j] = tile[c8 + j][n];
#pragma unroll
  for (int j = 0; j < 4; j++) hi[j] = tile[c8 + 4 + j][n];
  unsigned short* outp = hT + ((size_t)(b * N_ + nt * 64 + n)) * C_ + ct * CPG_ + c8;
  *reinterpret_cast<us4*>(outp) = lo;
  *reinterpret_cast<us4*>(outp + 4) = hi;
}

// ---------------------------------------------------------------------------
// Kernel 3: qkv GEMM, 128-n x 128-o blocks. grid 768 (1D XCD-affine):
// idx = ot*128 + nt*4 + b, ot in [0,6). Each block entirely within one of
// Q/K/V (sec = ot>>1). Wave: 32 o (2 r-groups), acc[2][8]. Staged hT tile
// shared by 6 ot-blocks (was 12).
// ---------------------------------------------------------------------------
__global__ __launch_bounds__(256) void qkv_gemm(
    const unsigned short* __restrict__ hT, const unsigned short* __restrict__ wq,
    const float* __restrict__ qb,
    unsigned short* __restrict__ Qt, unsigned short* __restrict__ Kt,
    unsigned short* __restrict__ V) {
  int ot = blockIdx.x >> 7;
  int nt = (blockIdx.x & 127) >> 2;
  int b  = blockIdx.x & 3;
  int t = threadIdx.x;
  int wave = t >> 6, lane = t & 63, l15 = lane & 15, quad = lane >> 4, l7 = l15 & 7;

  __shared__ __align__(16) unsigned short sh[128 * C_];
  {
    int row0 = wave * 2 + (lane >> 5);
    int col8 = lane & 31;
    int src8 = (col8 & 24) | ((col8 & 7) ^ (row0 & 7));
    const unsigned short* gsrc = hT + ((size_t)(b * N_ + nt * 128 + row0)) * C_ + src8 * 8;
#pragma unroll
    for (int it = 0; it < 16; it++)
      dma16(gsrc + (size_t)it * 8 * C_, sh + (it * 8 + wave * 2) * C_);
  }

  f32x4 acc[2][8];
#pragma unroll
  for (int r = 0; r < 2; r++)
#pragma unroll
    for (int tt = 0; tt < 8; tt++) acc[r][tt] = (f32x4){0.f, 0.f, 0.f, 0.f};

  // weight rows: o = ot*128 + wave*32 + r*16 + l15 (global output index)
  const short8* arow[2];
#pragma unroll
  for (int r = 0; r < 2; r++)
    arow[r] = reinterpret_cast<const short8*>(
        wq + (size_t)(ot * 128 + wave * 32 + r * 16 + l15) * C_);

  asm volatile("s_waitcnt vmcnt(0)" ::: "memory");
  __syncthreads();

#pragma unroll
  for (int kk = 0; kk < 8; kk++) {
    int g = kk * 4 + quad;
    int col8 = (g & 24) | ((g & 7) ^ l7);
    short8 bfr[8];
#pragma unroll
    for (int tt = 0; tt < 8; tt++)
      bfr[tt] = *reinterpret_cast<const short8*>(&sh[(tt * 16 + l15) * C_ + col8 * 8]);
#pragma unroll
    for (int r = 0; r < 2; r++) {
      short8 a = arow[r][g];
#pragma unroll
      for (int tt = 0; tt < 8; tt++)
        acc[r][tt] = __builtin_amdgcn_mfma_f32_16x16x32_bf16(a, bfr[tt], acc[r][tt], 0, 0, 0);
    }
  }

  int sec = ot >> 1;                       // 0=Q, 1=K, 2=V
  int head = (ot & 1) * 2 + (wave >> 1);   // head index within batch
  int bh = b * NH_ + head;
  const float SC = 0.125f * 1.44269504088896340736f;  // 1/sqrt(hd) * log2(e)

#pragma unroll
  for (int r = 0; r < 2; r++) {
    int o_glob = ot * 128 + wave * 32 + r * 16;        // row base (bias index)
    int cw = (o_glob & 63) + quad * 4;                 // channel within head
    if (sec == 0) {
#pragma unroll
      for (int tt = 0; tt < 8; tt++) {
        int n = nt * 128 + tt * 16 + l15;
        us4 pk;
#pragma unroll
        for (int i = 0; i < 4; i++)
          pk[i] = f2bf((acc[r][tt][i] + qb[o_glob + quad * 4 + i]) * SC);
        *reinterpret_cast<us4*>(Qt + ((size_t)bh * N_ + n) * HD_ + cw) = pk;
      }
    } else if (sec == 1) {
#pragma unroll
      for (int tt = 0; tt < 8; tt++) {
        int n = nt * 128 + tt * 16 + l15;
        us4 pk;
#pragma unroll
        for (int i = 0; i < 4; i++)
          pk[i] = f2bf(acc[r][tt][i] + qb[o_glob + quad * 4 + i]);
        *reinterpret_cast<us4*>(Kt + ((size_t)bh * N_ + n) * HD_ + cw) = pk;
      }
    } else {
#pragma unroll
      for (int tt = 0; tt < 8; tt++) {
        int n = nt * 128 + tt * 16 + l15;
#pragma unroll
        for (int i = 0; i < 4; i++)
          V[((size_t)bh * HD_ + cw + i) * N_ + n] =
              f2bf(acc[r][tt][i] + qb[o_glob + quad * 4 + i]);
      }
    }
  }
}

// ---------------------------------------------------------------------------
// Kernel 4: flash attention (R10 version — at its HIP-source plateau).
// ---------------------------------------------------------------------------
__global__ __launch_bounds__(256, 2) void flash_attn(
    const unsigned short* __restrict__ Qt, const unsigned short* __restrict__ Kt,
    const unsigned short* __restrict__ Vv, unsigned short* __restrict__ aoT) {
  int bh = blockIdx.x & 15, qt = blockIdx.x >> 4;
  int b = bh >> 2, head = bh & 3;
  int t = threadIdx.x;
  int wave = t >> 6, lane = t & 63, l15 = lane & 15, quad = lane >> 4;
  int l7 = l15 & 7;
  int qsub = wave >> 1, khalf = wave & 1;

  const unsigned short* Qb = Qt + (size_t)bh * N_ * HD_;
  const unsigned short* Kb = Kt + (size_t)bh * N_ * HD_;
  const unsigned short* Vb = Vv + (size_t)bh * HD_ * N_;
  int q_base = qt * 128 + qsub * 64;

  __shared__ __align__(16) unsigned char smem[74752];
  unsigned short* Ks = (unsigned short*)smem;
  unsigned short* Vs = (unsigned short*)(smem + 32768);
  unsigned short* Ps = (unsigned short*)(smem + 65536);
  float* Obuf = (float*)smem;                 // qsub*4352 + c*68 + q
  float* lbuf = (float*)(smem + 34816);       // qsub*64 + q

  const short8 vones = {(short)0x3F80, (short)0x3F80, (short)0x3F80, (short)0x3F80,
                        (short)0x3F80, (short)0x3F80, (short)0x3F80, (short)0x3F80};

  short8 qf[4][2];
#pragma unroll
  for (int r = 0; r < 4; r++)
#pragma unroll
    for (int h = 0; h < 2; h++)
      qf[r][h] = *reinterpret_cast<const short8*>(
          Qb + (size_t)(q_base + r * 16 + l15) * HD_ + h * 32 + quad * 8);

  f32x4 oa[4][4], la[4];
#pragma unroll
  for (int r = 0; r < 4; r++) {
    la[r] = (f32x4){0.f, 0.f, 0.f, 0.f};
#pragma unroll
    for (int ct = 0; ct < 4; ct++) oa[r][ct] = (f32x4){0.f, 0.f, 0.f, 0.f};
  }

  int i8 = lane >> 3, e = lane & 7;
  int perm = (e ^ i8) * 8;   // XOR swizzle of 8-element groups
  int kvoff = (khalf * 2) * 4096;
  auto stage = [&](int kt2, int buf) {
    int m0 = khalf * 2048 + kt2 * 64;
    unsigned short* Kd = Ks + kvoff + buf * 4096;
    unsigned short* Vd = Vs + kvoff + buf * 4096;
#pragma unroll
    for (int cc = 0; cc < 4; cc++) {
      int c = qsub * 4 + cc;
      dma16(Kb + (size_t)(m0 + c * 8 + i8) * HD_ + perm, Kd + c * 512);
      dma16(Vb + (size_t)(c * 8 + i8) * N_ + m0 + perm, Vd + c * 512);
    }
  };

  stage(0, 0);

  unsigned short* Pw = Ps + wave * 16 * 72;

#pragma unroll 1
  for (int kt = 0; kt < 32; kt++) {
    int buf = kt & 1;
    if (kt + 1 < 32) {
      stage(kt + 1, buf ^ 1);                          // issue prefetch first
      asm volatile("s_waitcnt vmcnt(8)" ::: "memory"); // wait only tile kt's 8
    } else {
      asm volatile("s_waitcnt vmcnt(0)" ::: "memory");
    }
    __builtin_amdgcn_s_barrier();

    const unsigned short* Kbuf = Ks + kvoff + buf * 4096;
    const unsigned short* Vbuf = Vs + kvoff + buf * 4096;

    short8 kf[4][2], vf[4][2];
#pragma unroll
    for (int tt = 0; tt < 4; tt++)
#pragma unroll
      for (int kh2 = 0; kh2 < 2; kh2++) {
        kf[tt][kh2] = *reinterpret_cast<const short8*>(
            &Kbuf[(tt * 16 + l15) * 64 + (((kh2 * 4 + quad) ^ l7) * 8)]);
        vf[tt][kh2] = *reinterpret_cast<const short8*>(
            &Vbuf[(tt * 16 + l15) * 64 + (((kh2 * 4 + quad) ^ l7) * 8)]);
      }

#pragma unroll
    for (int r = 0; r < 4; r++) {
      f32x4 s[4];
#pragma unroll
      for (int tt = 0; tt < 4; tt++) {
        f32x4 z = (f32x4){0.f, 0.f, 0.f, 0.f};
        z = __builtin_amdgcn_mfma_f32_16x16x32_bf16(kf[tt][0], qf[r][0], z, 0, 0, 0);
        s[tt] = __builtin_amdgcn_mfma_f32_16x16x32_bf16(kf[tt][1], qf[r][1], z, 0, 0, 0);
      }
#pragma unroll
      for (int tt = 0; tt < 4; tt++) {
        union { unsigned u2[2]; us4 v; } w;
        w.u2[0] = pkbf2(__builtin_amdgcn_exp2f(s[tt][0]), __builtin_amdgcn_exp2f(s[tt][1]));
        w.u2[1] = pkbf2(__builtin_amdgcn_exp2f(s[tt][2]), __builtin_amdgcn_exp2f(s[tt][3]));
        *reinterpret_cast<us4*>(&Pw[l15 * 72 + tt * 16 + quad * 4]) = w.v;
      }
      short8 pf0 = *reinterpret_cast<const short8*>(&Pw[l15 * 72 + quad * 8]);
      short8 pf1 = *reinterpret_cast<const short8*>(&Pw[l15 * 72 + 32 + quad * 8]);
#pragma unroll
      for (int ct = 0; ct < 4; ct++) {
        oa[r][ct] = __builtin_amdgcn_mfma_f32_16x16x32_bf16(vf[ct][0], pf0, oa[r][ct], 0, 0, 0);
        oa[r][ct] = __builtin_amdgcn_mfma_f32_16x16x32_bf16(vf[ct][1], pf1, oa[r][ct], 0, 0, 0);
      }
      la[r] = __builtin_amdgcn_mfma_f32_16x16x32_bf16(vones, pf0, la[r], 0, 0, 0);
      la[r] = __builtin_amdgcn_mfma_f32_16x16x32_bf16(vones, pf1, la[r], 0, 0, 0);
    }
  }

  // ---- merge the two key-halves (exact: plain add, no max-sub) ----
  __builtin_amdgcn_s_barrier();
  if (khalf == 1) {
#pragma unroll
    for (int r = 0; r < 4; r++) {
#pragma unroll
      for (int ct = 0; ct < 4; ct++)
#pragma unroll
        for (int i = 0; i < 4; i++)
          Obuf[qsub * 4352 + (ct * 16 + quad * 4 + i) * 68 + r * 16 + l15] = oa[r][ct][i];
      if (quad == 0) lbuf[qsub * 64 + r * 16 + l15] = la[r][0];
    }
  }
  __builtin_amdgcn_s_barrier();
  if (khalf == 0) {
#pragma unroll
    for (int r = 0; r < 4; r++) {
      float inv = 1.0f / (la[r][0] + lbuf[qsub * 64 + r * 16 + l15]);
      int n = q_base + r * 16 + l15;
#pragma unroll
      for (int ct = 0; ct < 4; ct++) {
        const float* ob = &Obuf[qsub * 4352 + (ct * 16 + quad * 4) * 68 + r * 16 + l15];
        union { unsigned u2[2]; us4 v; } w;
        w.u2[0] = pkbf2((oa[r][ct][0] + ob[0]) * inv, (oa[r][ct][1] + ob[68]) * inv);
        w.u2[1] = pkbf2((oa[r][ct][2] + ob[136]) * inv, (oa[r][ct][3] + ob[204]) * inv);
        *reinterpret_cast<us4*>(
            aoT + ((size_t)(b * N_ + n)) * C_ + head * HD_ + ct * 16 + quad * 4) = w.v;
      }
    }
  }
}

// ---------------------------------------------------------------------------
// Kernel 5: proj GEMM + bias + residual, 128-n tiles, 1D XCD-aware grid
// (512 blocks): idx = ot*128 + nt*4 + b.
// ---------------------------------------------------------------------------
__global__ __launch_bounds__(256) void proj_gemm(
    const unsigned short* __restrict__ aoT, const unsigned short* __restrict__ wp,
    const float* __restrict__ pb, const float* __restrict__ x,
    float* __restrict__ out) {
  int ot = blockIdx.x >> 7;
  int nt = (blockIdx.x & 127) >> 2;
  int b  = blockIdx.x & 3;
  int t = threadIdx.x;
  int wave = t >> 6, lane = t & 63, l15 = lane & 15, quad = lane >> 4, l7 = l15 & 7;
  int o_base = ot * 64 + wave * 16;

  __shared__ __align__(16) unsigned short sh[128 * C_];
  {
    int row0 = wave * 2 + (lane >> 5);
    int col8 = lane & 31;
    int src8 = (col8 & 24) | ((col8 & 7) ^ (row0 & 7));
    const unsigned short* gsrc = aoT + ((size_t)(b * N_ + nt * 128 + row0)) * C_ + src8 * 8;
#pragma unroll
    for (int it = 0; it < 16; it++)
      dma16(gsrc + (size_t)it * 8 * C_, sh + (it * 8 + wave * 2) * C_);
  }

  f32x4 acc[8];
#pragma unroll
  for (int tt = 0; tt < 8; tt++) acc[tt] = (f32x4){0.f, 0.f, 0.f, 0.f};

  const short8* arow = reinterpret_cast<const short8*>(wp + (size_t)(o_base + l15) * C_);

  asm volatile("s_waitcnt vmcnt(0)" ::: "memory");
  __syncthreads();

#pragma unroll
  for (int kk = 0; kk < 8; kk++) {
    short8 a = arow[kk * 4 + quad];
    int g = kk * 4 + quad;
    int col8 = (g & 24) | ((g & 7) ^ l7);
#pragma unroll
    for (int tt = 0; tt < 8; tt++) {
      short8 bf = *reinterpret_cast<const short8*>(&sh[(tt * 16 + l15) * C_ + col8 * 8]);
      acc[tt] = __builtin_amdgcn_mfma_f32_16x16x32_bf16(a, bf, acc[tt], 0, 0, 0);
    }
  }
#pragma unroll
  for (int tt = 0; tt < 8; tt++) {
    int n = nt * 128 + tt * 16 + l15;
#pragma unroll
    for (int i = 0; i < 4; i++) {
      int o = o_base + quad * 4 + i;
      size_t idx = ((size_t)(b * C_ + o)) * N_ + n;
      out[idx] = acc[tt][i] + pb[o] + x[idx];
    }
  }
}

// ---------------------------------------------------------------------------
extern "C" void kernel_launch(void* const* d_in, const int* in_sizes, int n_in,
                              void* d_out, int out_size, void* d_ws, size_t ws_size,
                              hipStream_t stream) {
  const float* x      = (const float*)d_in[0];
  const float* norm_w = (const float*)d_in[1];
  const float* norm_b = (const float*)d_in[2];
  const float* qkv_w  = (const float*)d_in[3];
  const float* qkv_b  = (const float*)d_in[4];
  const float* proj_w = (const float*)d_in[5];
  const float* proj_b = (const float*)d_in[6];
  float* out = (float*)d_out;

  char* ws = (char*)d_ws;
  size_t off = 0;
  auto alloc = [&](size_t bytes) { size_t o = off; off = (off + bytes + 255) & ~(size_t)255; return o; };
  size_t off_partial = alloc(512 * 2 * sizeof(float));
  size_t off_stats   = alloc(32 * 2 * sizeof(float));   // unused (layout stability)
  size_t off_wq      = alloc((size_t)768 * 256 * 2);
  size_t off_wp      = alloc((size_t)256 * 256 * 2);
  size_t off_hT      = alloc((size_t)B_ * N_ * C_ * 2);
  size_t off_Qt      = alloc((size_t)B_ * NH_ * N_ * HD_ * 2);
  size_t off_Kt      = alloc((size_t)B_ * NH_ * N_ * HD_ * 2);
  size_t off_V       = alloc((size_t)B_ * NH_ * HD_ * N_ * 2);
  size_t off_aoT     = alloc((size_t)B_ * N_ * C_ * 2);
  (void)off_stats;

  float* partial = (float*)(ws + off_partial);
  unsigned short* wq  = (unsigned short*)(ws + off_wq);
  unsigned short* wp  = (unsigned short*)(ws + off_wp);
  unsigned short* hT  = (unsigned short*)(ws + off_hT);
  unsigned short* Qt  = (unsigned short*)(ws + off_Qt);
  unsigned short* Kt  = (unsigned short*)(ws + off_Kt);
  unsigned short* V   = (unsigned short*)(ws + off_V);
  unsigned short* aoT = (unsigned short*)(ws + off_aoT);

  gn_partial_cvt<<<1280, 256, 0, stream>>>(x, partial, qkv_w, proj_w, wq, wp);
  gn_apply<<<dim3(64, 8, 4), 256, 0, stream>>>(x, norm_w, norm_b, partial, hT);
  qkv_gemm<<<768, 256, 0, stream>>>(hT, wq, qkv_b, Qt, Kt, V);
  flash_attn<<<512, 256, 0, stream>>>(Qt, Kt, V, aoT);
  proj_gemm<<<512, 256, 0, stream>>>(aoT, wp, proj_b, x, out);
}